// Round 8
// baseline (1237.940 us; speedup 1.0000x reference)
//
#include <hip/hip_runtime.h>
#include <hip/hip_fp16.h>
#include <math.h>

// Problem constants
#define ROWS   8192        // B*L = 2*4096
#define DIMK   2048
#define HIDN   4096
#define QCH    128
#define NCHUNK 32          // L/Q per batch

typedef __attribute__((ext_vector_type(8))) short short8;
typedef __attribute__((ext_vector_type(8))) _Float16 half8;
typedef __attribute__((ext_vector_type(4))) float floatx4;

static __device__ inline unsigned short f2h(float f){
  union { _Float16 h; unsigned short u; } v; v.h = (_Float16)f; return v.u;
}
static __device__ inline float h2f(unsigned short u){
  union { unsigned short u; _Float16 h; } v; v.u = u; return (float)v.h;
}
static __device__ inline void async_cp16(const void* g, void* l){
  __builtin_amdgcn_global_load_lds((const __attribute__((address_space(1))) void*)g,
                                   (__attribute__((address_space(3))) void*)l, 16, 0, 0);
}

// ---------------- cast fp32 -> fp16 (packed x4) ----------------
__global__ void k_cast(const float* __restrict__ in, unsigned short* __restrict__ out, int n4){
  int i = blockIdx.x * 256 + threadIdx.x;
  if (i < n4){
    float4 v = ((const float4*)in)[i];
    unsigned long long p = (unsigned long long)f2h(v.x)
                         | ((unsigned long long)f2h(v.y) << 16)
                         | ((unsigned long long)f2h(v.z) << 32)
                         | ((unsigned long long)f2h(v.w) << 48);
    ((unsigned long long*)out)[i] = p;
  }
}

// ---------------- exact fp32 dt_raw = x @ W_in[8448:8512].T ----------------
__global__ __launch_bounds__(256)
void k_dtraw(const float* __restrict__ x, const float* __restrict__ Win,
             float* __restrict__ dtraw){
  __shared__ float ws[64 * 132];
  const int t = threadIdx.x;
  const int lane = t & 63, w = t >> 6;
  const int r0 = blockIdx.x * 16;
  const int rw = __builtin_amdgcn_readfirstlane(r0 + w * 4);
  float a0 = 0.f, a1 = 0.f, a2 = 0.f, a3 = 0.f;
  for (int k0 = 0; k0 < DIMK; k0 += 128){
    __syncthreads();                              // previous tile's reads done
#pragma unroll
    for (int l = 0; l < 8; l++){
      int fidx = (l * 256 + t) * 4;               // 0..8191 floats
      int row = fidx >> 7, col = fidx & 127;
      *(float4*)&ws[row * 132 + col] =
          *(const float4*)&Win[(size_t)(8448 + row) * DIMK + k0 + col];
    }
    __syncthreads();
    const float* xp = x + (size_t)rw * DIMK + k0;
#pragma unroll 8
    for (int kk = 0; kk < 128; kk += 4){
      float4 wv = *(const float4*)&ws[lane * 132 + kk];
      float4 v0 = *(const float4*)&xp[kk];
      float4 v1 = *(const float4*)&xp[DIMK + kk];
      float4 v2 = *(const float4*)&xp[2*DIMK + kk];
      float4 v3 = *(const float4*)&xp[3*DIMK + kk];
      a0 += wv.x*v0.x + wv.y*v0.y + wv.z*v0.z + wv.w*v0.w;
      a1 += wv.x*v1.x + wv.y*v1.y + wv.z*v1.z + wv.w*v1.w;
      a2 += wv.x*v2.x + wv.y*v2.y + wv.z*v2.z + wv.w*v2.w;
      a3 += wv.x*v3.x + wv.y*v3.y + wv.z*v3.z + wv.w*v3.w;
    }
  }
  dtraw[(size_t)rw * 64 + lane]       = a0;
  dtraw[((size_t)rw + 1) * 64 + lane] = a1;
  dtraw[((size_t)rw + 2) * 64 + lane] = a2;
  dtraw[((size_t)rw + 3) * 64 + lane] = a3;
}

// ---------------- asm LDS read helpers (opaque to alias analysis) ----------------
static __device__ inline unsigned ldsaddr(const void* p){
  return (unsigned)(size_t)(const __attribute__((address_space(3))) void*)p;
}
static __device__ inline floatx4 dsr128(unsigned a){
  floatx4 d;
  asm volatile("ds_read_b128 %0, %1" : "=v"(d) : "v"(a));
  return d;
}
static __device__ inline half8 as_h8(floatx4 f){
  union { floatx4 f; half8 h; } u; u.f = f; return u.h;
}

// ---------------- 256x128 MFMA GEMM core, BK=32, triple-buffer, 2 blocks/CU ----
// 8 waves (4M x 2N), per-wave 64x64 = 4x4 16x16 frags (acc 64 VGPR) ->
// __launch_bounds__(512,4): 4 waves/SIMD (2 blocks/CU). R7's 2-waves/SIMD
// phase-locked structure exposed every barrier/lgkm drain (MfmaUtil 38%);
// here the sibling block's waves fill those gaps (m114 cross-wave overlap),
// and barriers per unit-K halve (one phase per BK=32 tile).
// LDS 3 x (256+128)x32 fp16 = 72 KiB. Stage T+2 goes to buffer (T+2)%3, last
// read at tile T-1 and drained by T-1's lgkmcnt(0) + barrier -> race-free.
// T2 swizzle (4 slots/row): linear slot = q ^ ((row>>1)&3) -> 2-way = free
// (row&3 variant is 4-way); applied pre-swizzled on the global source (linear
// LDS dest, rule #21) and on every ds_read.
// vmcnt: 3 stage-instrs/tile; steady state outstanding 6 -> vmcnt(3) = tile
// T+1 landed, T+2 in flight. ds_reads inline-asm, un-fenced across barrier;
// MFMA phase opens lgkmcnt(0) + sched_barrier(0) (rule #18).
template<int KD>
__device__ inline void gemm_core32(const unsigned short* __restrict__ A,
                                   const unsigned short* __restrict__ B,
                                   int row0, int col0,
                                   unsigned short* sA, unsigned short* sB,
                                   floatx4 (&acc)[4][4], int t){
  const int lane = t & 63, wid = t >> 6;
  const int wm = wid >> 1, wn = wid & 1;
  const int quad = lane >> 4, l16 = lane & 15;
  constexpr int NT = KD / 32;
  const int sr  = t >> 2;                     // staging row (B; A adds i*128)
  const int ssl = (t & 3) ^ ((t >> 3) & 3);   // pre-swizzled source 16B slot

  auto stageA = [&](int b, int kt){
    unsigned short* dst = sA + b*8192;
    const unsigned short* src = A + (size_t)row0 * KD + kt*32 + ssl*8;
#pragma unroll
    for (int i = 0; i < 2; i++)
      async_cp16(src + (size_t)(i*128 + sr) * KD, dst + ((size_t)i*512 + t)*8);
  };
  auto stageB = [&](int b, int kt){
    unsigned short* dst = sB + b*4096;
    const unsigned short* src = B + (size_t)col0 * KD + kt*32 + ssl*8;
    async_cp16(src + (size_t)sr * KD, dst + (size_t)t*8);
  };

  const unsigned sAb = ldsaddr(sA), sBb = ldsaddr(sB);
  const unsigned rsw = (unsigned)((quad ^ ((l16 >> 1) & 3)) * 8);
  floatx4 af[4], bf[4];

  // prologue: tiles 0,1 into buffers 0,1 (6 load-instrs)
  stageA(0,0); stageB(0,0);
  stageA(1,1); stageB(1,1);
  asm volatile("s_waitcnt vmcnt(3)" ::: "memory");   // tile0 landed
  __builtin_amdgcn_s_barrier();

  int b = 0;
  for (int T = 0; T < NT; T++){
    const unsigned aBase = sAb + 2u*((unsigned)(b*8192 + (wm*64 + l16)*32) + rsw);
    const unsigned bBase = sBb + 2u*((unsigned)(b*4096 + (wn*64 + l16)*32) + rsw);
#pragma unroll
    for (int m = 0; m < 4; m++) af[m] = dsr128(aBase + 2u*(unsigned)(m*16*32));
#pragma unroll
    for (int n = 0; n < 4; n++) bf[n] = dsr128(bBase + 2u*(unsigned)(n*16*32));
    int b2 = b + 2; if (b2 >= 3) b2 -= 3;
    if (T + 2 < NT){
      stageA(b2, T+2); stageB(b2, T+2);
      asm volatile("s_waitcnt vmcnt(3)" ::: "memory");   // tile T+1 landed
    } else if (T + 1 < NT){
      asm volatile("s_waitcnt vmcnt(0)" ::: "memory");
    }
    __builtin_amdgcn_s_barrier();
    asm volatile("s_waitcnt lgkmcnt(0)" ::: "memory");
    __builtin_amdgcn_sched_barrier(0);
    __builtin_amdgcn_s_setprio(1);
#pragma unroll
    for (int m = 0; m < 4; m++)
#pragma unroll
      for (int n = 0; n < 4; n++)
        acc[m][n] = __builtin_amdgcn_mfma_f32_16x16x32_f16(
            as_h8(af[m]), as_h8(bf[n]), acc[m][n], 0, 0, 0);
    __builtin_amdgcn_s_setprio(0);
    __builtin_amdgcn_s_barrier();
    b = b + 1; if (b >= 3) b = 0;
  }
}

// ---------------- GEMM1: routed fp16 epilogue (z | xs | bc) ----------------
__global__ __launch_bounds__(512, 4)
void k_gemm1(const unsigned short* __restrict__ A, const unsigned short* __restrict__ B,
             unsigned short* __restrict__ zbuf, unsigned short* __restrict__ xsraw,
             unsigned short* __restrict__ bcraw){
  __shared__ __align__(16) unsigned short sA[3*256*32];
  __shared__ __align__(16) unsigned short sB[3*128*32];
  const int t = threadIdx.x;
  // bijective XCD swizzle: 2112 = 8 * 264
  int swz = (blockIdx.x % 8) * 264 + blockIdx.x / 8;
  const int row0 = (swz & 31) * 256, col0 = (swz >> 5) * 128;
  floatx4 acc[4][4] = {};
  gemm_core32<DIMK>(A, B, row0, col0, sA, sB, acc, t);
  const int lane = t & 63, wid = t >> 6;
  const int wm = wid >> 1, wn = wid & 1;
  const int quad = lane >> 4, l16 = lane & 15;
  unsigned short* dst; int cbase, ldd;
  if (col0 < 4096){ dst = zbuf; cbase = 0; ldd = 4096; }
  else if (col0 < 8192){ dst = xsraw; cbase = 4096; ldd = 4096; }
  else { dst = bcraw; cbase = 8192; ldd = 256; }
#pragma unroll
  for (int m = 0; m < 4; m++)
#pragma unroll
    for (int n = 0; n < 4; n++){
      int rb = row0 + wm*64 + m*16 + quad*4;
      int cc = col0 + wn*64 + n*16 + l16 - cbase;
#pragma unroll
      for (int r = 0; r < 4; r++)
        dst[(size_t)(rb + r) * ldd + cc] = f2h(acc[m][n][r]);
    }
}

// ---------------- GEMM2: fp32 epilogue to d_out ----------------
__global__ __launch_bounds__(512, 4)
void k_gemm2(const unsigned short* __restrict__ A, const unsigned short* __restrict__ B,
             float* __restrict__ C){
  __shared__ __align__(16) unsigned short sA[3*256*32];
  __shared__ __align__(16) unsigned short sB[3*128*32];
  const int t = threadIdx.x;
  // bijective XCD swizzle: 512 = 8 * 64
  int swz = (blockIdx.x % 8) * 64 + blockIdx.x / 8;
  const int row0 = (swz & 31) * 256, col0 = (swz >> 5) * 128;
  floatx4 acc[4][4] = {};
  gemm_core32<HIDN>(A, B, row0, col0, sA, sB, acc, t);
  const int lane = t & 63, wid = t >> 6;
  const int wm = wid >> 1, wn = wid & 1;
  const int quad = lane >> 4, l16 = lane & 15;
#pragma unroll
  for (int m = 0; m < 4; m++)
#pragma unroll
    for (int n = 0; n < 4; n++){
      int rb = row0 + wm*64 + m*16 + quad*4;
      int cc = col0 + wn*64 + n*16 + l16;
#pragma unroll
      for (int r = 0; r < 4; r++)
        C[(size_t)(rb + r) * DIMK + cc] = acc[m][n][r];
    }
}

// ---------------- extract pre-conv xs halo rows (3 per chunk boundary) ----------------
// slot s holds row bc*128 - 3 + s
__global__ void k_halo(const unsigned short* __restrict__ xsraw, unsigned short* __restrict__ halo){
  int col = blockIdx.x * 256 + threadIdx.x;   // [0,4096)
  int slot = blockIdx.y, bc = blockIdx.z;
  long r = (long)bc * QCH - 3 + slot;
  if (r >= 0)
    halo[((size_t)bc * 3 + slot) * 4096 + col] = xsraw[(size_t)r * 4096 + col];
}

// ---------------- causal conv (K=4) + SiLU on B/C columns only ----------------
__global__ void k_convbc(const unsigned short* __restrict__ bcraw, const float* __restrict__ cw,
                         unsigned short* __restrict__ bcc){
  int row = blockIdx.x, c = threadIdx.x;      // c in [0,256)
  int tl = row & 4095;
  const float4 wv = *(const float4*)&cw[(size_t)(4096 + c) * 4];
  const unsigned short* col = bcraw + c;
  size_t rb = (size_t)row * 256;
  float a = h2f(col[rb]) * wv.w;
  if (tl >= 1) a += h2f(col[rb - 256]) * wv.z;
  if (tl >= 2) a += h2f(col[rb - 512]) * wv.y;
  if (tl >= 3) a += h2f(col[rb - 768]) * wv.x;
  bcc[rb + c] = f2h(a / (1.f + __expf(-a)));
}

// ---------------- softplus(dt) + per-chunk cumsum of dt*A ----------------
__global__ void k_dtcum(const float* __restrict__ dtraw, const float* __restrict__ dtbias,
                        const float* __restrict__ Alog, float* __restrict__ dtb,
                        float* __restrict__ cumb){
  int bc = blockIdx.x;        // [0,64)
  int h  = threadIdx.x;       // [0,64)
  float bias = dtbias[h];
  float A = -__expf(Alog[h]);
  float run = 0.f;
  size_t rowb = (size_t)bc * QCH;
  for (int q = 0; q < QCH; q++){
    float dr = dtraw[(rowb + q) * 64 + h] + bias;
    float dt = dr > 20.f ? dr : log1pf(__expf(dr));
    dtb[(rowb + q) * 64 + h] = dt;
    run += dt * A;
    cumb[(rowb + q) * 64 + h] = run;
  }
}

// ---------------- fused conv+SiLU staging of xs tile, transposed (P x Q) ----------------
// tap t-k, row rowb+q-k: in-chunk if q>=k, else halo slot (q-k+3)
__device__ inline void stage_xsT(const unsigned short* __restrict__ xsraw,
                                 const unsigned short* __restrict__ halo,
                                 const float* cws, unsigned short* xsT,
                                 int bc, int h, int t){
  const size_t rowb = (size_t)bc * QCH;
  const int tl0 = (bc & 31) * QCH;
#pragma unroll
  for (int it = 0; it < 2; it++){
    int idx = it * 256 + t;
    int q = idx & 127, p0 = (idx >> 7) * 16;
    int tl = tl0 + q;
    const unsigned short* cur = xsraw + (rowb + q) * 4096 + h * 64 + p0;
    const unsigned short* hb  = halo + ((size_t)bc * 3) * 4096 + h * 64 + p0;
    const unsigned short* r1 = (q >= 1) ? cur - 4096     : hb + 2 * 4096;
    const unsigned short* r2 = (q >= 2) ? cur - 2 * 4096 : hb + (size_t)(q + 1) * 4096;
    const unsigned short* r3 = (q >= 3) ? cur - 3 * 4096 : hb + (size_t)q * 4096;
    float f1 = (tl >= 1) ? 1.f : 0.f;
    float f2 = (tl >= 2) ? 1.f : 0.f;
    float f3 = (tl >= 3) ? 1.f : 0.f;
    short8 c0 = *(const short8*)cur, c1 = *(const short8*)(cur + 8);
    short8 a0 = *(const short8*)r1,  a1 = *(const short8*)(r1 + 8);
    short8 b0 = *(const short8*)r2,  b1 = *(const short8*)(r2 + 8);
    short8 d0 = *(const short8*)r3,  d1 = *(const short8*)(r3 + 8);
#pragma unroll
    for (int j = 0; j < 16; j++){
      int col = p0 + j;
      const float* wp = cws + col * 4;
      float vc = h2f((unsigned short)(j < 8 ? c0[j] : c1[j-8]));
      float v1 = h2f((unsigned short)(j < 8 ? a0[j] : a1[j-8]));
      float v2 = h2f((unsigned short)(j < 8 ? b0[j] : b1[j-8]));
      float v3 = h2f((unsigned short)(j < 8 ? d0[j] : d1[j-8]));
      float a = vc * wp[3] + f1 * v1 * wp[2] + f2 * v2 * wp[1] + f3 * v3 * wp[0];
      float s = a / (1.f + __expf(-a));
      xsT[col * 128 + q] = f2h(s);
    }
  }
}

// ---------------- per-(chunk,head): CB -> M -> Yd; + Yoff from Sprev; y = Yd+Yoff+D*xs ----------------
// xsc = POST-conv xs (chunk2 wrote it back in place over xsraw) in [row][col] layout.
__global__ __launch_bounds__(256, 2)
void k_chunk1(const unsigned short* __restrict__ xsc, const unsigned short* __restrict__ bcc,
              const float* __restrict__ dtb, const float* __restrict__ cumb,
              const float* __restrict__ Dp, const unsigned short* __restrict__ st,
              unsigned short* __restrict__ ybuf){
  __shared__ __align__(16) unsigned short Ml[128*128];
  __shared__ __align__(16) unsigned short xsT[64*128];
  __shared__ float cum_s[128], dt_s[128];
  const int blk = blockIdx.x, h = blk & 63, bc = blk >> 6;
  const size_t rowb = (size_t)bc * QCH;
  const int t = threadIdx.x, w = t >> 6, lane = t & 63, quad = lane >> 4, l16 = lane & 15;
  const int wrow = w * 32;
  if (t < 128){ cum_s[t] = cumb[(rowb + t)*64 + h]; dt_s[t] = dtb[(rowb + t)*64 + h]; }
  __syncthreads();
  // copy-transpose post-conv xs tile into xsT (no conv recompute)
#pragma unroll
  for (int it = 0; it < 2; it++){
    int idx = it * 256 + t;
    int q = idx & 127, p0 = (idx >> 7) * 16;
    const unsigned short* cur = xsc + (rowb + q) * 4096 + h * 64 + p0;
    short8 c0 = *(const short8*)cur, c1 = *(const short8*)(cur + 8);
#pragma unroll
    for (int j = 0; j < 16; j++)
      xsT[(p0 + j) * 128 + q] = (unsigned short)(j < 8 ? c0[j] : c1[j-8]);
  }
  // CB = C @ B^T from post-conv bcc
  floatx4 acc[2][8] = {};
  const unsigned short* Cb = bcc + rowb * 256 + 128;
  const unsigned short* Bb = bcc + rowb * 256;
#pragma unroll
  for (int ks = 0; ks < 4; ks++){
    half8 af[2];
#pragma unroll
    for (int i = 0; i < 2; i++)
      af[i] = *(const half8*)(Cb + (size_t)(wrow + i*16 + l16) * 256 + ks*32 + quad*8);
#pragma unroll
    for (int j = 0; j < 8; j++){
      half8 bfr = *(const half8*)(Bb + (size_t)(j*16 + l16) * 256 + ks*32 + quad*8);
#pragma unroll
      for (int i = 0; i < 2; i++)
        acc[i][j] = __builtin_amdgcn_mfma_f32_16x16x32_f16(af[i], bfr, acc[i][j], 0, 0, 0);
    }
  }
  // M = CB * exp(cum_i - cum_j) * dt_j, causal, -> LDS fp16
#pragma unroll
  for (int i = 0; i < 2; i++)
#pragma unroll
    for (int j = 0; j < 8; j++){
      int jc = j*16 + l16;
      float dtj = dt_s[jc], cj = cum_s[jc];
#pragma unroll
      for (int r = 0; r < 4; r++){
        int ir = wrow + i*16 + quad*4 + r;
        float m = (ir >= jc) ? acc[i][j][r] * __expf(cum_s[ir] - cj) * dtj : 0.f;
        Ml[ir * 128 + jc] = f2h(m);
      }
    }
  __syncthreads();
  // Yd = M @ xs
  floatx4 accY[2][4] = {};
#pragma unroll
  for (int ks = 0; ks < 4; ks++){
    half8 af[2], bfr[4];
#pragma unroll
    for (int i = 0; i < 2; i++)
      af[i] = *(const half8*)&Ml[(wrow + i*16 + l16)*128 + ks*32 + quad*8];
#pragma unroll
    for (int p = 0; p < 4; p++)
      bfr[p] = *(const half8*)&xsT[(p*16 + l16)*128 + ks*32 + quad*8];
#pragma unroll
    for (int i = 0; i < 2; i++)
#pragma unroll
      for (int p = 0; p < 4; p++)
        accY[i][p] = __builtin_amdgcn_mfma_f32_16x16x32_f16(af[i], bfr[p], accY[i][p], 0, 0, 0);
  }
  // ---- Yoff: stage Sprev (fp16) into Ml's LDS, then C @ Sprev^T ----
  __syncthreads();                       // all Yd reads of Ml done
  unsigned short* Sp = Ml;               // reuse (64*128 <= 128*128)
  {
    size_t base = ((size_t)bc * 64 + h) * 8192;
#pragma unroll
    for (int it = 0; it < 4; it++){
      int idx = (it * 256 + t) * 8;
      *(short8*)&Sp[idx] = *(const short8*)&st[base + idx];
    }
  }
  __syncthreads();
  floatx4 accO[2][4] = {};
#pragma unroll
  for (int ks = 0; ks < 4; ks++){
    half8 af[2], bfr[4];
#pragma unroll
    for (int i = 0; i < 2; i++)
      af[i] = *(const half8*)(Cb + (size_t)(wrow + i*16 + l16) * 256 + ks*32 + quad*8);
#pragma unroll
    for (int p = 0; p < 4; p++)
      bfr[p] = *(const half8*)&Sp[(p*16 + l16)*128 + ks*32 + quad*8];
#pragma unroll
    for (int i = 0; i < 2; i++)
#pragma unroll
      for (int p = 0; p < 4; p++)
        accO[i][p] = __builtin_amdgcn_mfma_f32_16x16x32_f16(af[i], bfr[p], accO[i][p], 0, 0, 0);
  }
  float Dh = Dp[h];
#pragma unroll
  for (int i = 0; i < 2; i++)
#pragma unroll
    for (int p = 0; p < 4; p++){
      int pc = p*16 + l16;
#pragma unroll
      for (int r = 0; r < 4; r++){
        int ir = wrow + i*16 + quad*4 + r;
        float y = accY[i][p][r] + __expf(cum_s[ir]) * accO[i][p][r] + Dh * h2f(xsT[pc*128 + ir]);
        ybuf[(rowb + ir) * (size_t)HIDN + h*64 + pc] = f2h(y);
      }
    }
}

// ---------------- per-(chunk,head): states[p][n] = sum_q xs[q][p]*wdec_q*B[q][n] ----------------
// Also writes POST-conv xs back over xsraw in place (consumed by k_chunk1).
__global__ __launch_bounds__(256, 2)
void k_chunk2(unsigned short* __restrict__ xsraw, const unsigned short* __restrict__ bcc,
              const unsigned short* __restrict__ halo, const float* __restrict__ cw,
              const float* __restrict__ dtb, const float* __restrict__ cumb,
              unsigned short* __restrict__ st){
  __shared__ __align__(16) unsigned short wBT[128*128];
  __shared__ __align__(16) unsigned short xsT[64*128];
  __shared__ float cum_s[128], dt_s[128];
  __shared__ float cws[64*4];
  const int blk = blockIdx.x, h = blk & 63, bc = blk >> 6;
  const size_t rowb = (size_t)bc * QCH;
  const int t = threadIdx.x, w = t >> 6, lane = t & 63, quad = lane >> 4, l16 = lane & 15;
  if (t < 128){ cum_s[t] = cumb[(rowb + t)*64 + h]; dt_s[t] = dtb[(rowb + t)*64 + h]; }
  if (t < 64) *(float4*)&cws[t*4] = *(const float4*)&cw[((size_t)h*64 + t)*4];
  __syncthreads();
  stage_xsT(xsraw, halo, cws, xsT, bc, h, t);
  __syncthreads();                 // all tap reads done before in-place overwrite
  // write post-conv xs back to global
#pragma unroll
  for (int it = 0; it < 2; it++){
    int idx = it * 256 + t;
    int q = idx & 127, p0 = (idx >> 7) * 16;
    short8 w0, w1;
#pragma unroll
    for (int j = 0; j < 8; j++){
      w0[j] = (short)xsT[(p0 + j) * 128 + q];
      w1[j] = (short)xsT[(p0 + 8 + j) * 128 + q];
    }
    unsigned short* g = xsraw + (rowb + q) * 4096 + h * 64 + p0;
    *(short8*)g = w0;
    *(short8*)(g + 8) = w1;
  }
  float clast = cum_s[127];
#pragma unroll
  for (int it = 0; it < 2; it++){                 // wBT[n][q] = B[q][n]*wdec_q
    int idx = it * 256 + t;
    int q = idx & 127, n0 = (idx >> 7) * 32;
    float wd = __expf(clast - cum_s[q]) * dt_s[q];
    const unsigned short* gp = bcc + (rowb + q) * 256 + n0;
#pragma unroll
    for (int c4 = 0; c4 < 4; c4++){
      short8 v = *(const short8*)(gp + c4*8);
#pragma unroll
      for (int jj = 0; jj < 8; jj++)
        wBT[(n0 + c4*8 + jj)*128 + q] = f2h(h2f((unsigned short)v[jj]) * wd);
    }
  }
  __syncthreads();
  floatx4 acc[8] = {};
#pragma unroll
  for (int ks = 0; ks < 4; ks++){
    half8 af = *(const half8*)&xsT[(w*16 + l16)*128 + ks*32 + quad*8];
#pragma unroll
    for (int j = 0; j < 8; j++){
      half8 bfr = *(const half8*)&wBT[(j*16 + l16)*128 + ks*32 + quad*8];
      acc[j] = __builtin_amdgcn_mfma_f32_16x16x32_f16(af, bfr, acc[j], 0, 0, 0);
    }
  }
  size_t base = ((size_t)bc * 64 + h) * 8192;
#pragma unroll
  for (int j = 0; j < 8; j++){
    int n = j*16 + l16;
#pragma unroll
    for (int r = 0; r < 4; r++){
      int p = w*16 + quad*4 + r;
      st[base + p*128 + n] = f2h(acc[j][r]);
    }
  }
}

// ---------------- sequential inter-chunk scan (fp16 states -> Sprev, in place) ----------------
__global__ void k_scan(unsigned short* __restrict__ st, const float* __restrict__ cumb){
  int id = blockIdx.x * 256 + threadIdx.x;  // [0, 2*64*64*128)
  int n = id & 127, p = (id >> 7) & 63, h = (id >> 13) & 63, b = id >> 19;
  float S = 0.f;
  for (int c = 0; c < NCHUNK; c++){
    int bc = b * NCHUNK + c;
    size_t idx = ((size_t)bc * 64 + h) * 8192 + (size_t)p * 128 + n;
    float dec = __expf(cumb[((size_t)bc * QCH + 127) * 64 + h]);
    float v = h2f(st[idx]);
    st[idx] = f2h(S);
    S = S * dec + v;
  }
}

// ---------------- gate y*silu(z) + RMSNorm, in-place fp16 ----------------
__global__ __launch_bounds__(256)
void k_gate(unsigned short* __restrict__ yb, const unsigned short* __restrict__ zb,
            const float* __restrict__ nw){
  __shared__ float red[4];
  int row = blockIdx.x, t = threadIdx.x;
  float vals[16], ss = 0.f;
#pragma unroll
  for (int it = 0; it < 16; it++){
    int c = it * 256 + t;
    float y = h2f(yb[(size_t)row * HIDN + c]);
    float z = h2f(zb[(size_t)row * HIDN + c]);
    float v = y * (z / (1.f + __expf(-z)));
    vals[it] = v; ss += v * v;
  }
  for (int o = 32; o > 0; o >>= 1) ss += __shfl_down(ss, o, 64);
  int w = t >> 6, lane = t & 63;
  if (lane == 0) red[w] = ss;
  __syncthreads();
  float scale = rsqrtf((red[0] + red[1] + red[2] + red[3]) / (float)HIDN + 1e-5f);
#pragma unroll
  for (int it = 0; it < 16; it++){
    int c = it * 256 + t;
    yb[(size_t)row * HIDN + c] = f2h(vals[it] * scale * nw[c]);
  }
}

extern "C" void kernel_launch(void* const* d_in, const int* in_sizes, int n_in,
                              void* d_out, int out_size, void* d_ws, size_t ws_size,
                              hipStream_t stream){
  const float* x      = (const float*)d_in[0];
  const float* Win    = (const float*)d_in[1];
  const float* convw  = (const float*)d_in[2];
  const float* dtbias = (const float*)d_in[3];
  const float* Alog   = (const float*)d_in[4];
  const float* Dp     = (const float*)d_in[5];
  const float* nw     = (const float*)d_in[6];
  const float* Wout   = (const float*)d_in[7];
  float* out = (float*)d_out;

  char* ws = (char*)d_ws;
  size_t off = 0;
  auto alloc = [&](size_t bytes)->void*{ void* p = ws + off; off += (bytes + 255) & ~(size_t)255; return p; };
  unsigned short* xw    = (unsigned short*)alloc((size_t)ROWS * DIMK * 2);   // 33.5 MB (dead after gemm1)
  unsigned short* winb  = (unsigned short*)alloc((size_t)8448 * DIMK * 2);   // 34.6 MB (dead after gemm1)
  float*          dtraw = (float*)alloc((size_t)ROWS * 64 * 4);              // 2.1 MB
  unsigned short* woutb = (unsigned short*)alloc((size_t)DIMK * HIDN * 2);   // 16.8 MB
  unsigned short* zbuf  = (unsigned short*)alloc((size_t)ROWS * HIDN * 2);   // 67.1 MB
  unsigned short* xsraw = (unsigned short*)alloc((size_t)ROWS * HIDN * 2);   // 67.1 MB (pre-conv xs -> post-conv xs -> y)
  unsigned short* bcraw = (unsigned short*)alloc((size_t)ROWS * 256 * 2);    // 4.2 MB
  unsigned short* bcc   = (unsigned short*)alloc((size_t)ROWS * 256 * 2);    // 4.2 MB
  unsigned short* halo  = (unsigned short*)alloc((size_t)64 * 3 * 4096 * 2); // 1.5 MB
  float*          dtb   = (float*)alloc((size_t)ROWS * 64 * 4);              // 2.1 MB
  float*          cumb  = (float*)alloc((size_t)ROWS * 64 * 4);              // 2.1 MB
  // total ~224.5 MiB; states (fp16, 67.1 MB) overlays dead xw+winb region
  unsigned short* st    = xw;
  unsigned short* ybuf  = xsraw;   // chunk1 writes y in-place over post-conv xs

  k_cast<<<(ROWS*DIMK/4 + 255)/256, 256, 0, stream>>>(x, xw, ROWS*DIMK/4);
  k_cast<<<(8448*DIMK/4 + 255)/256, 256, 0, stream>>>(Win, winb, 8448*DIMK/4);
  k_cast<<<(DIMK*HIDN/4 + 255)/256, 256, 0, stream>>>(Wout, woutb, DIMK*HIDN/4);
  k_dtraw<<<ROWS/16, 256, 0, stream>>>(x, Win, dtraw);
  k_gemm1<<<dim3(32*66), 512, 0, stream>>>(xw, winb, zbuf, xsraw, bcraw);
  k_halo<<<dim3(16, 3, 64), 256, 0, stream>>>(xsraw, halo);
  k_convbc<<<ROWS, 256, 0, stream>>>(bcraw, convw, bcc);
  k_dtcum<<<64, 64, 0, stream>>>(dtraw, dtbias, Alog, dtb, cumb);
  k_chunk2<<<4096, 256, 0, stream>>>(xsraw, bcc, halo, convw, dtb, cumb, st);
  k_scan<<<4096, 256, 0, stream>>>(st, cumb);
  k_chunk1<<<4096, 256, 0, stream>>>(xsraw, bcc, dtb, cumb, Dp, st, ybuf);
  k_gate<<<ROWS, 256, 0, stream>>>(ybuf, zbuf, nw);
  k_gemm2<<<dim3(32*16), 512, 0, stream>>>(ybuf, woutb, out);
}

// Round 9
// 1085.101 us; speedup vs baseline: 1.1409x; 1.1409x over previous
//
#include <hip/hip_runtime.h>
#include <hip/hip_fp16.h>
#include <math.h>

// Problem constants
#define ROWS   8192        // B*L = 2*4096
#define DIMK   2048
#define HIDN   4096
#define QCH    128
#define NCHUNK 32          // L/Q per batch

typedef __attribute__((ext_vector_type(8))) short short8;
typedef __attribute__((ext_vector_type(8))) _Float16 half8;
typedef __attribute__((ext_vector_type(4))) float floatx4;

static __device__ inline unsigned short f2h(float f){
  union { _Float16 h; unsigned short u; } v; v.h = (_Float16)f; return v.u;
}
static __device__ inline float h2f(unsigned short u){
  union { unsigned short u; _Float16 h; } v; v.u = u; return (float)v.h;
}
static __device__ inline void async_cp16(const void* g, void* l){
  __builtin_amdgcn_global_load_lds((const __attribute__((address_space(1))) void*)g,
                                   (__attribute__((address_space(3))) void*)l, 16, 0, 0);
}

// ---------------- cast fp32 -> fp16 (packed x4) ----------------
__global__ void k_cast(const float* __restrict__ in, unsigned short* __restrict__ out, int n4){
  int i = blockIdx.x * 256 + threadIdx.x;
  if (i < n4){
    float4 v = ((const float4*)in)[i];
    unsigned long long p = (unsigned long long)f2h(v.x)
                         | ((unsigned long long)f2h(v.y) << 16)
                         | ((unsigned long long)f2h(v.z) << 32)
                         | ((unsigned long long)f2h(v.w) << 48);
    ((unsigned long long*)out)[i] = p;
  }
}

// ---------------- exact fp32 dt_raw = x @ W_in[8448:8512].T ----------------
__global__ __launch_bounds__(256)
void k_dtraw(const float* __restrict__ x, const float* __restrict__ Win,
             float* __restrict__ dtraw){
  __shared__ float ws[64 * 132];
  const int t = threadIdx.x;
  const int lane = t & 63, w = t >> 6;
  const int r0 = blockIdx.x * 16;
  const int rw = __builtin_amdgcn_readfirstlane(r0 + w * 4);
  float a0 = 0.f, a1 = 0.f, a2 = 0.f, a3 = 0.f;
  for (int k0 = 0; k0 < DIMK; k0 += 128){
    __syncthreads();                              // previous tile's reads done
#pragma unroll
    for (int l = 0; l < 8; l++){
      int fidx = (l * 256 + t) * 4;               // 0..8191 floats
      int row = fidx >> 7, col = fidx & 127;
      *(float4*)&ws[row * 132 + col] =
          *(const float4*)&Win[(size_t)(8448 + row) * DIMK + k0 + col];
    }
    __syncthreads();
    const float* xp = x + (size_t)rw * DIMK + k0;
#pragma unroll 8
    for (int kk = 0; kk < 128; kk += 4){
      float4 wv = *(const float4*)&ws[lane * 132 + kk];
      float4 v0 = *(const float4*)&xp[kk];
      float4 v1 = *(const float4*)&xp[DIMK + kk];
      float4 v2 = *(const float4*)&xp[2*DIMK + kk];
      float4 v3 = *(const float4*)&xp[3*DIMK + kk];
      a0 += wv.x*v0.x + wv.y*v0.y + wv.z*v0.z + wv.w*v0.w;
      a1 += wv.x*v1.x + wv.y*v1.y + wv.z*v1.z + wv.w*v1.w;
      a2 += wv.x*v2.x + wv.y*v2.y + wv.z*v2.z + wv.w*v2.w;
      a3 += wv.x*v3.x + wv.y*v3.y + wv.z*v3.z + wv.w*v3.w;
    }
  }
  dtraw[(size_t)rw * 64 + lane]       = a0;
  dtraw[((size_t)rw + 1) * 64 + lane] = a1;
  dtraw[((size_t)rw + 2) * 64 + lane] = a2;
  dtraw[((size_t)rw + 3) * 64 + lane] = a3;
}

// ---------------- asm LDS read helpers (opaque to alias analysis) ----------------
static __device__ inline unsigned ldsaddr(const void* p){
  return (unsigned)(size_t)(const __attribute__((address_space(3))) void*)p;
}
static __device__ inline floatx4 dsr128(unsigned a){
  floatx4 d;
  asm volatile("ds_read_b128 %0, %1" : "=v"(d) : "v"(a));
  return d;
}
static __device__ inline half8 as_h8(floatx4 f){
  union { floatx4 f; half8 h; } u; u.f = f; return u.h;
}

// ---------------- 256x256 MFMA GEMM core, 4-phase/K-tile (R7 local optimum) ----
// 8 waves (2M x 4N), per-wave 128x64 = 8x4 16x16 frags. BK=64.
// LDS: 2 buffers x [256][64] fp16 for A and B = 128 KiB (1 block/CU).
// T2 swizzle: 16B slot q of row r stored at q^(r&7); pre-swizzled global source
// (linear LDS dest, rule #21) + same XOR on every ds_read. 0 bank conflicts.
// ds_reads inline-asm (opaque to alias analysis -> no lgkmcnt drain before the
// same-phase global_load_lds); reads cross the raw s_barrier un-drained; each
// MFMA phase opens with s_waitcnt lgkmcnt(0) + sched_barrier(0) (rule #18).
// Verified R7: 329 us gemm1 (864 TF), MfmaUtil 38%. R8's BK=32/2-blocks-per-CU
// variant regressed (370 us, FETCH 2x) -> this is the kept structure.
template<int KD>
__device__ inline void gemm256_core(const unsigned short* __restrict__ A,
                                    const unsigned short* __restrict__ B,
                                    int row0, int col0,
                                    unsigned short* sA, unsigned short* sB,
                                    floatx4 (&acc)[8][4], int t){
  const int lane = t & 63, wid = t >> 6;
  const int wm = wid >> 2, wn = wid & 3;
  const int quad = lane >> 4, l16 = lane & 15;
  const int srow  = t >> 3;                    // 0..63: row within 64-row stage block
  const int sslot = (t & 7) ^ (srow & 7);      // pre-swizzled global 16B slot
  constexpr int NT = KD / 64;

  auto stageA = [&](int d, int half, int kt){
    unsigned short* dst = sA + d*256*64 + half*128*64;
    const unsigned short* src = A + (size_t)(row0 + half*128) * KD + kt*64;
#pragma unroll
    for (int i = 0; i < 2; i++)
      async_cp16(src + (size_t)(i*64 + srow) * KD + sslot*8,
                 dst + ((size_t)i*512 + t)*8);
  };
  auto stageB = [&](int d, int half, int kt){
    unsigned short* dst = sB + d*256*64 + half*128*64;
    const unsigned short* src = B + (size_t)(col0 + half*128) * KD + kt*64;
#pragma unroll
    for (int i = 0; i < 2; i++)
      async_cp16(src + (size_t)(i*64 + srow) * KD + sslot*8,
                 dst + ((size_t)i*512 + t)*8);
  };

  const unsigned sAbase = ldsaddr(sA), sBbase = ldsaddr(sB);
  floatx4 af[8][2], bf[4][2];
  auto rdA = [&](unsigned base, int fr, int ks) -> floatx4 {
    return dsr128(base + 2u*(unsigned)((fr*16 + l16)*64 + (((ks*4+quad)^(l16&7))*8)));
  };
  auto rdB = [&](unsigned base, int fc, int ks) -> floatx4 {
    return dsr128(base + 2u*(unsigned)((fc*16 + l16)*64 + (((ks*4+quad)^(l16&7))*8)));
  };
  auto mmac = [&](int mh, int nh){
    __builtin_amdgcn_s_setprio(1);
#pragma unroll
    for (int mm = 0; mm < 4; mm++)
#pragma unroll
      for (int nn = 0; nn < 2; nn++)
#pragma unroll
        for (int ks = 0; ks < 2; ks++)
          acc[mh*4+mm][nh*2+nn] = __builtin_amdgcn_mfma_f32_16x16x32_f16(
              as_h8(af[mh*4+mm][ks]), as_h8(bf[nh*2+nn][ks]), acc[mh*4+mm][nh*2+nn], 0, 0, 0);
    __builtin_amdgcn_s_setprio(0);
  };

  // prologue: tile0 full -> buf0 (8 loads), tile1 A -> buf1 (4 loads)
  stageA(0,0,0); stageA(0,1,0); stageB(0,0,0); stageB(0,1,0);
  stageA(1,0,1); stageA(1,1,1);
  asm volatile("s_waitcnt vmcnt(4)" ::: "memory");   // tile0's 8 loads landed
  __builtin_amdgcn_s_barrier();

  for (int T = 0; T < NT; T++){
    const int cur = T & 1;
    const unsigned aAd = sAbase + 2u*(unsigned)(cur*256*64 + wm*128*64);
    const unsigned bAd = sBbase + 2u*(unsigned)(cur*256*64 + wn*64*64);
    // ---------------- phase 0: read A0-3,B0-1 | stage B-top(T+1) ----------------
#pragma unroll
    for (int fr = 0; fr < 4; fr++)
#pragma unroll
      for (int ks = 0; ks < 2; ks++)
        af[fr][ks] = rdA(aAd, fr, ks);
#pragma unroll
    for (int fc = 0; fc < 2; fc++)
#pragma unroll
      for (int ks = 0; ks < 2; ks++)
        bf[fc][ks] = rdB(bAd, fc, ks);
    if (T + 1 < NT) stageB(cur^1, 0, T+1);
    __builtin_amdgcn_s_barrier();
    asm volatile("s_waitcnt lgkmcnt(0)" ::: "memory");
    __builtin_amdgcn_sched_barrier(0);
    mmac(0, 0);
    __builtin_amdgcn_s_barrier();
    // ---------------- phase 1: read A4-7 | stage B-bot(T+1) ----------------
#pragma unroll
    for (int fr = 4; fr < 8; fr++)
#pragma unroll
      for (int ks = 0; ks < 2; ks++)
        af[fr][ks] = rdA(aAd, fr, ks);
    if (T + 1 < NT) stageB(cur^1, 1, T+1);
    __builtin_amdgcn_s_barrier();
    asm volatile("s_waitcnt lgkmcnt(0)" ::: "memory");
    __builtin_amdgcn_sched_barrier(0);
    mmac(1, 0);
    __builtin_amdgcn_s_barrier();
    // ---------------- phase 2: read B2-3 ----------------
#pragma unroll
    for (int fc = 2; fc < 4; fc++)
#pragma unroll
      for (int ks = 0; ks < 2; ks++)
        bf[fc][ks] = rdB(bAd, fc, ks);
    __builtin_amdgcn_s_barrier();
    asm volatile("s_waitcnt lgkmcnt(0)" ::: "memory");
    __builtin_amdgcn_sched_barrier(0);
    mmac(0, 1);
    __builtin_amdgcn_s_barrier();
    // ---------------- phase 3: stage A(T+2), counted vmcnt ----------------
    if (T + 2 < NT){
      stageA(cur, 0, T+2); stageA(cur, 1, T+2);
      asm volatile("s_waitcnt vmcnt(4)" ::: "memory");
    } else if (T + 1 < NT){
      asm volatile("s_waitcnt vmcnt(0)" ::: "memory");
    }
    __builtin_amdgcn_s_barrier();
    mmac(1, 1);
    __builtin_amdgcn_s_barrier();
  }
}

// ---------------- GEMM1: routed fp16 epilogue (z | xs | bc) ----------------
__global__ __launch_bounds__(512, 2)
void k_gemm1(const unsigned short* __restrict__ A, const unsigned short* __restrict__ B,
             unsigned short* __restrict__ zbuf, unsigned short* __restrict__ xsraw,
             unsigned short* __restrict__ bcraw){
  __shared__ __align__(16) unsigned short sA[2*256*64];
  __shared__ __align__(16) unsigned short sB[2*256*64];
  const int t = threadIdx.x;
  // bijective XCD swizzle: 1056 = 8 * 132
  int swz = (blockIdx.x % 8) * 132 + blockIdx.x / 8;
  const int row0 = (swz & 31) * 256, col0 = (swz >> 5) * 256;
  floatx4 acc[8][4] = {};
  gemm256_core<DIMK>(A, B, row0, col0, sA, sB, acc, t);
  const int lane = t & 63, wid = t >> 6;
  const int wm = wid >> 2, wn = wid & 3;
  const int quad = lane >> 4, l16 = lane & 15;
  unsigned short* dst; int cbase, ldd;
  if (col0 < 4096){ dst = zbuf; cbase = 0; ldd = 4096; }
  else if (col0 < 8192){ dst = xsraw; cbase = 4096; ldd = 4096; }
  else { dst = bcraw; cbase = 8192; ldd = 256; }
#pragma unroll
  for (int m = 0; m < 8; m++)
#pragma unroll
    for (int n = 0; n < 4; n++){
      int rb = row0 + wm*128 + m*16 + quad*4;
      int cc = col0 + wn*64 + n*16 + l16 - cbase;
#pragma unroll
      for (int r = 0; r < 4; r++)
        dst[(size_t)(rb + r) * ldd + cc] = f2h(acc[m][n][r]);
    }
}

// ---------------- GEMM2: fp32 epilogue to d_out ----------------
__global__ __launch_bounds__(512, 2)
void k_gemm2(const unsigned short* __restrict__ A, const unsigned short* __restrict__ B,
             float* __restrict__ C){
  __shared__ __align__(16) unsigned short sA[2*256*64];
  __shared__ __align__(16) unsigned short sB[2*256*64];
  const int t = threadIdx.x;
  // bijective XCD swizzle: 256 = 8 * 32
  int swz = (blockIdx.x % 8) * 32 + blockIdx.x / 8;
  const int row0 = (swz & 31) * 256, col0 = (swz >> 5) * 256;
  floatx4 acc[8][4] = {};
  gemm256_core<HIDN>(A, B, row0, col0, sA, sB, acc, t);
  const int lane = t & 63, wid = t >> 6;
  const int wm = wid >> 2, wn = wid & 3;
  const int quad = lane >> 4, l16 = lane & 15;
#pragma unroll
  for (int m = 0; m < 8; m++)
#pragma unroll
    for (int n = 0; n < 4; n++){
      int rb = row0 + wm*128 + m*16 + quad*4;
      int cc = col0 + wn*64 + n*16 + l16;
#pragma unroll
      for (int r = 0; r < 4; r++)
        C[(size_t)(rb + r) * DIMK + cc] = acc[m][n][r];
    }
}

// ---------------- extract pre-conv xs halo rows (3 per chunk boundary) ----------------
// slot s holds row bc*128 - 3 + s
__global__ void k_halo(const unsigned short* __restrict__ xsraw, unsigned short* __restrict__ halo){
  int col = blockIdx.x * 256 + threadIdx.x;   // [0,4096)
  int slot = blockIdx.y, bc = blockIdx.z;
  long r = (long)bc * QCH - 3 + slot;
  if (r >= 0)
    halo[((size_t)bc * 3 + slot) * 4096 + col] = xsraw[(size_t)r * 4096 + col];
}

// ---------------- causal conv (K=4) + SiLU on B/C columns only ----------------
__global__ void k_convbc(const unsigned short* __restrict__ bcraw, const float* __restrict__ cw,
                         unsigned short* __restrict__ bcc){
  int row = blockIdx.x, c = threadIdx.x;      // c in [0,256)
  int tl = row & 4095;
  const float4 wv = *(const float4*)&cw[(size_t)(4096 + c) * 4];
  const unsigned short* col = bcraw + c;
  size_t rb = (size_t)row * 256;
  float a = h2f(col[rb]) * wv.w;
  if (tl >= 1) a += h2f(col[rb - 256]) * wv.z;
  if (tl >= 2) a += h2f(col[rb - 512]) * wv.y;
  if (tl >= 3) a += h2f(col[rb - 768]) * wv.x;
  bcc[rb + c] = f2h(a / (1.f + __expf(-a)));
}

// ---------------- softplus(dt) + per-chunk cumsum of dt*A ----------------
__global__ void k_dtcum(const float* __restrict__ dtraw, const float* __restrict__ dtbias,
                        const float* __restrict__ Alog, float* __restrict__ dtb,
                        float* __restrict__ cumb){
  int bc = blockIdx.x;        // [0,64)
  int h  = threadIdx.x;       // [0,64)
  float bias = dtbias[h];
  float A = -__expf(Alog[h]);
  float run = 0.f;
  size_t rowb = (size_t)bc * QCH;
  for (int q = 0; q < QCH; q++){
    float dr = dtraw[(rowb + q) * 64 + h] + bias;
    float dt = dr > 20.f ? dr : log1pf(__expf(dr));
    dtb[(rowb + q) * 64 + h] = dt;
    run += dt * A;
    cumb[(rowb + q) * 64 + h] = run;
  }
}

// ---------------- fused conv+SiLU staging of xs tile, transposed (P x Q) ----------------
// tap t-k, row rowb+q-k: in-chunk if q>=k, else halo slot (q-k+3)
__device__ inline void stage_xsT(const unsigned short* __restrict__ xsraw,
                                 const unsigned short* __restrict__ halo,
                                 const float* cws, unsigned short* xsT,
                                 int bc, int h, int t){
  const size_t rowb = (size_t)bc * QCH;
  const int tl0 = (bc & 31) * QCH;
#pragma unroll
  for (int it = 0; it < 2; it++){
    int idx = it * 256 + t;
    int q = idx & 127, p0 = (idx >> 7) * 16;
    int tl = tl0 + q;
    const unsigned short* cur = xsraw + (rowb + q) * 4096 + h * 64 + p0;
    const unsigned short* hb  = halo + ((size_t)bc * 3) * 4096 + h * 64 + p0;
    const unsigned short* r1 = (q >= 1) ? cur - 4096     : hb + 2 * 4096;
    const unsigned short* r2 = (q >= 2) ? cur - 2 * 4096 : hb + (size_t)(q + 1) * 4096;
    const unsigned short* r3 = (q >= 3) ? cur - 3 * 4096 : hb + (size_t)q * 4096;
    float f1 = (tl >= 1) ? 1.f : 0.f;
    float f2 = (tl >= 2) ? 1.f : 0.f;
    float f3 = (tl >= 3) ? 1.f : 0.f;
    short8 c0 = *(const short8*)cur, c1 = *(const short8*)(cur + 8);
    short8 a0 = *(const short8*)r1,  a1 = *(const short8*)(r1 + 8);
    short8 b0 = *(const short8*)r2,  b1 = *(const short8*)(r2 + 8);
    short8 d0 = *(const short8*)r3,  d1 = *(const short8*)(r3 + 8);
#pragma unroll
    for (int j = 0; j < 16; j++){
      int col = p0 + j;
      const float* wp = cws + col * 4;
      float vc = h2f((unsigned short)(j < 8 ? c0[j] : c1[j-8]));
      float v1 = h2f((unsigned short)(j < 8 ? a0[j] : a1[j-8]));
      float v2 = h2f((unsigned short)(j < 8 ? b0[j] : b1[j-8]));
      float v3 = h2f((unsigned short)(j < 8 ? d0[j] : d1[j-8]));
      float a = vc * wp[3] + f1 * v1 * wp[2] + f2 * v2 * wp[1] + f3 * v3 * wp[0];
      float s = a / (1.f + __expf(-a));
      xsT[col * 128 + q] = f2h(s);
    }
  }
}

// ---------------- per-(chunk,head): CB -> M -> Yd; + Yoff from Sprev; y = Yd+Yoff+D*xs ----------------
// xsc = POST-conv xs (chunk2 wrote it back in place over xsraw) in [row][col] layout.
__global__ __launch_bounds__(256, 2)
void k_chunk1(const unsigned short* __restrict__ xsc, const unsigned short* __restrict__ bcc,
              const float* __restrict__ dtb, const float* __restrict__ cumb,
              const float* __restrict__ Dp, const unsigned short* __restrict__ st,
              unsigned short* __restrict__ ybuf){
  __shared__ __align__(16) unsigned short Ml[128*128];
  __shared__ __align__(16) unsigned short xsT[64*128];
  __shared__ float cum_s[128], dt_s[128];
  const int blk = blockIdx.x, h = blk & 63, bc = blk >> 6;
  const size_t rowb = (size_t)bc * QCH;
  const int t = threadIdx.x, w = t >> 6, lane = t & 63, quad = lane >> 4, l16 = lane & 15;
  const int wrow = w * 32;
  if (t < 128){ cum_s[t] = cumb[(rowb + t)*64 + h]; dt_s[t] = dtb[(rowb + t)*64 + h]; }
  __syncthreads();
  // copy-transpose post-conv xs tile into xsT (no conv recompute)
#pragma unroll
  for (int it = 0; it < 2; it++){
    int idx = it * 256 + t;
    int q = idx & 127, p0 = (idx >> 7) * 16;
    const unsigned short* cur = xsc + (rowb + q) * 4096 + h * 64 + p0;
    short8 c0 = *(const short8*)cur, c1 = *(const short8*)(cur + 8);
#pragma unroll
    for (int j = 0; j < 16; j++)
      xsT[(p0 + j) * 128 + q] = (unsigned short)(j < 8 ? c0[j] : c1[j-8]);
  }
  // CB = C @ B^T from post-conv bcc
  floatx4 acc[2][8] = {};
  const unsigned short* Cb = bcc + rowb * 256 + 128;
  const unsigned short* Bb = bcc + rowb * 256;
#pragma unroll
  for (int ks = 0; ks < 4; ks++){
    half8 af[2];
#pragma unroll
    for (int i = 0; i < 2; i++)
      af[i] = *(const half8*)(Cb + (size_t)(wrow + i*16 + l16) * 256 + ks*32 + quad*8);
#pragma unroll
    for (int j = 0; j < 8; j++){
      half8 bfr = *(const half8*)(Bb + (size_t)(j*16 + l16) * 256 + ks*32 + quad*8);
#pragma unroll
      for (int i = 0; i < 2; i++)
        acc[i][j] = __builtin_amdgcn_mfma_f32_16x16x32_f16(af[i], bfr, acc[i][j], 0, 0, 0);
    }
  }
  // M = CB * exp(cum_i - cum_j) * dt_j, causal, -> LDS fp16
#pragma unroll
  for (int i = 0; i < 2; i++)
#pragma unroll
    for (int j = 0; j < 8; j++){
      int jc = j*16 + l16;
      float dtj = dt_s[jc], cj = cum_s[jc];
#pragma unroll
      for (int r = 0; r < 4; r++){
        int ir = wrow + i*16 + quad*4 + r;
        float m = (ir >= jc) ? acc[i][j][r] * __expf(cum_s[ir] - cj) * dtj : 0.f;
        Ml[ir * 128 + jc] = f2h(m);
      }
    }
  __syncthreads();
  // Yd = M @ xs
  floatx4 accY[2][4] = {};
#pragma unroll
  for (int ks = 0; ks < 4; ks++){
    half8 af[2], bfr[4];
#pragma unroll
    for (int i = 0; i < 2; i++)
      af[i] = *(const half8*)&Ml[(wrow + i*16 + l16)*128 + ks*32 + quad*8];
#pragma unroll
    for (int p = 0; p < 4; p++)
      bfr[p] = *(const half8*)&xsT[(p*16 + l16)*128 + ks*32 + quad*8];
#pragma unroll
    for (int i = 0; i < 2; i++)
#pragma unroll
      for (int p = 0; p < 4; p++)
        accY[i][p] = __builtin_amdgcn_mfma_f32_16x16x32_f16(af[i], bfr[p], accY[i][p], 0, 0, 0);
  }
  // ---- Yoff: stage Sprev (fp16) into Ml's LDS, then C @ Sprev^T ----
  __syncthreads();                       // all Yd reads of Ml done
  unsigned short* Sp = Ml;               // reuse (64*128 <= 128*128)
  {
    size_t base = ((size_t)bc * 64 + h) * 8192;
#pragma unroll
    for (int it = 0; it < 4; it++){
      int idx = (it * 256 + t) * 8;
      *(short8*)&Sp[idx] = *(const short8*)&st[base + idx];
    }
  }
  __syncthreads();
  floatx4 accO[2][4] = {};
#pragma unroll
  for (int ks = 0; ks < 4; ks++){
    half8 af[2], bfr[4];
#pragma unroll
    for (int i = 0; i < 2; i++)
      af[i] = *(const half8*)(Cb + (size_t)(wrow + i*16 + l16) * 256 + ks*32 + quad*8);
#pragma unroll
    for (int p = 0; p < 4; p++)
      bfr[p] = *(const half8*)&Sp[(p*16 + l16)*128 + ks*32 + quad*8];
#pragma unroll
    for (int i = 0; i < 2; i++)
#pragma unroll
      for (int p = 0; p < 4; p++)
        accO[i][p] = __builtin_amdgcn_mfma_f32_16x16x32_f16(af[i], bfr[p], accO[i][p], 0, 0, 0);
  }
  float Dh = Dp[h];
#pragma unroll
  for (int i = 0; i < 2; i++)
#pragma unroll
    for (int p = 0; p < 4; p++){
      int pc = p*16 + l16;
#pragma unroll
      for (int r = 0; r < 4; r++){
        int ir = wrow + i*16 + quad*4 + r;
        float y = accY[i][p][r] + __expf(cum_s[ir]) * accO[i][p][r] + Dh * h2f(xsT[pc*128 + ir]);
        ybuf[(rowb + ir) * (size_t)HIDN + h*64 + pc] = f2h(y);
      }
    }
}

// ---------------- per-(chunk,head): states[p][n] = sum_q xs[q][p]*wdec_q*B[q][n] ----------------
// Also writes POST-conv xs back over xsraw in place (consumed by k_chunk1).
__global__ __launch_bounds__(256, 2)
void k_chunk2(unsigned short* __restrict__ xsraw, const unsigned short* __restrict__ bcc,
              const unsigned short* __restrict__ halo, const float* __restrict__ cw,
              const float* __restrict__ dtb, const float* __restrict__ cumb,
              unsigned short* __restrict__ st){
  __shared__ __align__(16) unsigned short wBT[128*128];
  __shared__ __align__(16) unsigned short xsT[64*128];
  __shared__ float cum_s[128], dt_s[128];
  __shared__ float cws[64*4];
  const int blk = blockIdx.x, h = blk & 63, bc = blk >> 6;
  const size_t rowb = (size_t)bc * QCH;
  const int t = threadIdx.x, w = t >> 6, lane = t & 63, quad = lane >> 4, l16 = lane & 15;
  if (t < 128){ cum_s[t] = cumb[(rowb + t)*64 + h]; dt_s[t] = dtb[(rowb + t)*64 + h]; }
  if (t < 64) *(float4*)&cws[t*4] = *(const float4*)&cw[((size_t)h*64 + t)*4];
  __syncthreads();
  stage_xsT(xsraw, halo, cws, xsT, bc, h, t);
  __syncthreads();                 // all tap reads done before in-place overwrite
  // write post-conv xs back to global
#pragma unroll
  for (int it = 0; it < 2; it++){
    int idx = it * 256 + t;
    int q = idx & 127, p0 = (idx >> 7) * 16;
    short8 w0, w1;
#pragma unroll
    for (int j = 0; j < 8; j++){
      w0[j] = (short)xsT[(p0 + j) * 128 + q];
      w1[j] = (short)xsT[(p0 + 8 + j) * 128 + q];
    }
    unsigned short* g = xsraw + (rowb + q) * 4096 + h * 64 + p0;
    *(short8*)g = w0;
    *(short8*)(g + 8) = w1;
  }
  float clast = cum_s[127];
#pragma unroll
  for (int it = 0; it < 2; it++){                 // wBT[n][q] = B[q][n]*wdec_q
    int idx = it * 256 + t;
    int q = idx & 127, n0 = (idx >> 7) * 32;
    float wd = __expf(clast - cum_s[q]) * dt_s[q];
    const unsigned short* gp = bcc + (rowb + q) * 256 + n0;
#pragma unroll
    for (int c4 = 0; c4 < 4; c4++){
      short8 v = *(const short8*)(gp + c4*8);
#pragma unroll
      for (int jj = 0; jj < 8; jj++)
        wBT[(n0 + c4*8 + jj)*128 + q] = f2h(h2f((unsigned short)v[jj]) * wd);
    }
  }
  __syncthreads();
  floatx4 acc[8] = {};
#pragma unroll
  for (int ks = 0; ks < 4; ks++){
    half8 af = *(const half8*)&xsT[(w*16 + l16)*128 + ks*32 + quad*8];
#pragma unroll
    for (int j = 0; j < 8; j++){
      half8 bfr = *(const half8*)&wBT[(j*16 + l16)*128 + ks*32 + quad*8];
      acc[j] = __builtin_amdgcn_mfma_f32_16x16x32_f16(af, bfr, acc[j], 0, 0, 0);
    }
  }
  size_t base = ((size_t)bc * 64 + h) * 8192;
#pragma unroll
  for (int j = 0; j < 8; j++){
    int n = j*16 + l16;
#pragma unroll
    for (int r = 0; r < 4; r++){
      int p = w*16 + quad*4 + r;
      st[base + p*128 + n] = f2h(acc[j][r]);
    }
  }
}

// ---------------- sequential inter-chunk scan (fp16 states -> Sprev, in place) ----------------
// 2 adjacent n per thread (uint load/store, full 4B/lane width); per-element
// arithmetic identical to the scalar version -> bit-identical output.
__global__ void k_scan(unsigned short* __restrict__ st, const float* __restrict__ cumb){
  int id = blockIdx.x * 256 + threadIdx.x;  // [0, 2*64*64*64)
  int n2 = id & 63, p = (id >> 6) & 63, h = (id >> 12) & 63, b = id >> 18;
  float S0 = 0.f, S1 = 0.f;
  for (int c = 0; c < NCHUNK; c++){
    int bc = b * NCHUNK + c;
    size_t idx = ((size_t)bc * 64 + h) * 8192 + (size_t)p * 128 + n2 * 2;
    float dec = __expf(cumb[((size_t)bc * QCH + 127) * 64 + h]);
    unsigned v = *(const unsigned*)&st[idx];
    float v0 = h2f((unsigned short)(v & 0xffff));
    float v1 = h2f((unsigned short)(v >> 16));
    unsigned o = (unsigned)f2h(S0) | ((unsigned)f2h(S1) << 16);
    *(unsigned*)&st[idx] = o;
    S0 = S0 * dec + v0;
    S1 = S1 * dec + v1;
  }
}

// ---------------- gate y*silu(z) + RMSNorm, in-place fp16 (vectorized G13) ----
// thread t owns 16 contiguous cols -> short8 loads/stores, 32B/lane coalesced.
__global__ __launch_bounds__(256)
void k_gate(unsigned short* __restrict__ yb, const unsigned short* __restrict__ zb,
            const float* __restrict__ nw){
  __shared__ float red[4];
  int row = blockIdx.x, t = threadIdx.x;
  size_t base = (size_t)row * HIDN + t * 16;
  short8 y0 = *(const short8*)&yb[base], y1 = *(const short8*)&yb[base + 8];
  short8 z0 = *(const short8*)&zb[base], z1 = *(const short8*)&zb[base + 8];
  float vals[16], ss = 0.f;
#pragma unroll
  for (int j = 0; j < 8; j++){
    float y = h2f((unsigned short)y0[j]);
    float z = h2f((unsigned short)z0[j]);
    float v = y * (z / (1.f + __expf(-z)));
    vals[j] = v; ss += v * v;
  }
#pragma unroll
  for (int j = 0; j < 8; j++){
    float y = h2f((unsigned short)y1[j]);
    float z = h2f((unsigned short)z1[j]);
    float v = y * (z / (1.f + __expf(-z)));
    vals[8 + j] = v; ss += v * v;
  }
  for (int o = 32; o > 0; o >>= 1) ss += __shfl_down(ss, o, 64);
  int w = t >> 6, lane = t & 63;
  if (lane == 0) red[w] = ss;
  __syncthreads();
  float scale = rsqrtf((red[0] + red[1] + red[2] + red[3]) / (float)HIDN + 1e-5f);
  const float4 nw0 = *(const float4*)&nw[t*16];
  const float4 nw1 = *(const float4*)&nw[t*16 + 4];
  const float4 nw2 = *(const float4*)&nw[t*16 + 8];
  const float4 nw3 = *(const float4*)&nw[t*16 + 12];
  float nwv[16] = { nw0.x, nw0.y, nw0.z, nw0.w, nw1.x, nw1.y, nw1.z, nw1.w,
                    nw2.x, nw2.y, nw2.z, nw2.w, nw3.x, nw3.y, nw3.z, nw3.w };
  short8 o0, o1;
#pragma unroll
  for (int j = 0; j < 8; j++){
    o0[j] = (short)f2h(vals[j] * scale * nwv[j]);
    o1[j] = (short)f2h(vals[8 + j] * scale * nwv[8 + j]);
  }
  *(short8*)&yb[base]     = o0;
  *(short8*)&yb[base + 8] = o1;
}

extern "C" void kernel_launch(void* const* d_in, const int* in_sizes, int n_in,
                              void* d_out, int out_size, void* d_ws, size_t ws_size,
                              hipStream_t stream){
  const float* x      = (const float*)d_in[0];
  const float* Win    = (const float*)d_in[1];
  const float* convw  = (const float*)d_in[2];
  const float* dtbias = (const float*)d_in[3];
  const float* Alog   = (const float*)d_in[4];
  const float* Dp     = (const float*)d_in[5];
  const float* nw     = (const float*)d_in[6];
  const float* Wout   = (const float*)d_in[7];
  float* out = (float*)d_out;

  char* ws = (char*)d_ws;
  size_t off = 0;
  auto alloc = [&](size_t bytes)->void*{ void* p = ws + off; off += (bytes + 255) & ~(size_t)255; return p; };
  unsigned short* xw    = (unsigned short*)alloc((size_t)ROWS * DIMK * 2);   // 33.5 MB (dead after gemm1)
  unsigned short* winb  = (unsigned short*)alloc((size_t)8448 * DIMK * 2);   // 34.6 MB (dead after gemm1)
  float*          dtraw = (float*)alloc((size_t)ROWS * 64 * 4);              // 2.1 MB
  unsigned short* woutb = (unsigned short*)alloc((size_t)DIMK * HIDN * 2);   // 16.8 MB
  unsigned short* zbuf  = (unsigned short*)alloc((size_t)ROWS * HIDN * 2);   // 67.1 MB
  unsigned short* xsraw = (unsigned short*)alloc((size_t)ROWS * HIDN * 2);   // 67.1 MB (pre-conv xs -> post-conv xs -> y)
  unsigned short* bcraw = (unsigned short*)alloc((size_t)ROWS * 256 * 2);    // 4.2 MB
  unsigned short* bcc   = (unsigned short*)alloc((size_t)ROWS * 256 * 2);    // 4.2 MB
  unsigned short* halo  = (unsigned short*)alloc((size_t)64 * 3 * 4096 * 2); // 1.5 MB
  float*          dtb   = (float*)alloc((size_t)ROWS * 64 * 4);              // 2.1 MB
  float*          cumb  = (float*)alloc((size_t)ROWS * 64 * 4);              // 2.1 MB
  // total ~224.5 MiB; states (fp16, 67.1 MB) overlays dead xw+winb region
  unsigned short* st    = xw;
  unsigned short* ybuf  = xsraw;   // chunk1 writes y in-place over post-conv xs

  k_cast<<<(ROWS*DIMK/4 + 255)/256, 256, 0, stream>>>(x, xw, ROWS*DIMK/4);
  k_cast<<<(8448*DIMK/4 + 255)/256, 256, 0, stream>>>(Win, winb, 8448*DIMK/4);
  k_cast<<<(DIMK*HIDN/4 + 255)/256, 256, 0, stream>>>(Wout, woutb, DIMK*HIDN/4);
  k_dtraw<<<ROWS/16, 256, 0, stream>>>(x, Win, dtraw);
  k_gemm1<<<dim3(33*32), 512, 0, stream>>>(xw, winb, zbuf, xsraw, bcraw);
  k_halo<<<dim3(16, 3, 64), 256, 0, stream>>>(xsraw, halo);
  k_convbc<<<ROWS, 256, 0, stream>>>(bcraw, convw, bcc);
  k_dtcum<<<64, 64, 0, stream>>>(dtraw, dtbias, Alog, dtb, cumb);
  k_chunk2<<<4096, 256, 0, stream>>>(xsraw, bcc, halo, convw, dtb, cumb, st);
  k_scan<<<2048, 256, 0, stream>>>(st, cumb);
  k_chunk1<<<4096, 256, 0, stream>>>(xsraw, bcc, dtb, cumb, Dp, st, ybuf);
  k_gate<<<ROWS, 256, 0, stream>>>(ybuf, zbuf, nw);
  k_gemm2<<<dim3(8*32), 512, 0, stream>>>(ybuf, woutb, out);
}

// Round 10
// 1083.161 us; speedup vs baseline: 1.1429x; 1.0018x over previous
//
#include <hip/hip_runtime.h>
#include <hip/hip_fp16.h>
#include <math.h>

// Problem constants
#define ROWS   8192        // B*L = 2*4096
#define DIMK   2048
#define HIDN   4096
#define QCH    128
#define NCHUNK 32          // L/Q per batch

typedef __attribute__((ext_vector_type(8))) short short8;
typedef __attribute__((ext_vector_type(8))) _Float16 half8;
typedef __attribute__((ext_vector_type(4))) float floatx4;

static __device__ inline unsigned short f2h(float f){
  union { _Float16 h; unsigned short u; } v; v.h = (_Float16)f; return v.u;
}
static __device__ inline float h2f(unsigned short u){
  union { unsigned short u; _Float16 h; } v; v.u = u; return (float)v.h;
}
static __device__ inline void async_cp16(const void* g, void* l){
  __builtin_amdgcn_global_load_lds((const __attribute__((address_space(1))) void*)g,
                                   (__attribute__((address_space(3))) void*)l, 16, 0, 0);
}

// ---------------- merged fp32 -> fp16 cast for x, W_in[0:8448], W_out ----------
// range-dispatch: [0,16384) xw | [16384,33280) winb | [33280,41472) woutb
__global__ void k_prep(const float* __restrict__ x, const float* __restrict__ Win,
                       const float* __restrict__ Wout, unsigned short* __restrict__ xw,
                       unsigned short* __restrict__ winb, unsigned short* __restrict__ woutb){
  int blk = blockIdx.x, t = threadIdx.x;
  const float* src; unsigned short* dst; int i;
  if (blk < 16384){ src = x;    dst = xw;    i = blk * 256 + t; }
  else if (blk < 33280){ src = Win;  dst = winb;  i = (blk - 16384) * 256 + t; }
  else { src = Wout; dst = woutb; i = (blk - 33280) * 256 + t; }
  float4 v = ((const float4*)src)[i];
  unsigned long long p = (unsigned long long)f2h(v.x)
                       | ((unsigned long long)f2h(v.y) << 16)
                       | ((unsigned long long)f2h(v.z) << 32)
                       | ((unsigned long long)f2h(v.w) << 48);
  ((unsigned long long*)dst)[i] = p;
}

// ---------------- exact fp32 dt_raw = x @ W_in[8448:8512].T ----------------
__global__ __launch_bounds__(256)
void k_dtraw(const float* __restrict__ x, const float* __restrict__ Win,
             float* __restrict__ dtraw){
  __shared__ float ws[64 * 132];
  const int t = threadIdx.x;
  const int lane = t & 63, w = t >> 6;
  const int r0 = blockIdx.x * 16;
  const int rw = __builtin_amdgcn_readfirstlane(r0 + w * 4);
  float a0 = 0.f, a1 = 0.f, a2 = 0.f, a3 = 0.f;
  for (int k0 = 0; k0 < DIMK; k0 += 128){
    __syncthreads();                              // previous tile's reads done
#pragma unroll
    for (int l = 0; l < 8; l++){
      int fidx = (l * 256 + t) * 4;               // 0..8191 floats
      int row = fidx >> 7, col = fidx & 127;
      *(float4*)&ws[row * 132 + col] =
          *(const float4*)&Win[(size_t)(8448 + row) * DIMK + k0 + col];
    }
    __syncthreads();
    const float* xp = x + (size_t)rw * DIMK + k0;
#pragma unroll 8
    for (int kk = 0; kk < 128; kk += 4){
      float4 wv = *(const float4*)&ws[lane * 132 + kk];
      float4 v0 = *(const float4*)&xp[kk];
      float4 v1 = *(const float4*)&xp[DIMK + kk];
      float4 v2 = *(const float4*)&xp[2*DIMK + kk];
      float4 v3 = *(const float4*)&xp[3*DIMK + kk];
      a0 += wv.x*v0.x + wv.y*v0.y + wv.z*v0.z + wv.w*v0.w;
      a1 += wv.x*v1.x + wv.y*v1.y + wv.z*v1.z + wv.w*v1.w;
      a2 += wv.x*v2.x + wv.y*v2.y + wv.z*v2.z + wv.w*v2.w;
      a3 += wv.x*v3.x + wv.y*v3.y + wv.z*v3.z + wv.w*v3.w;
    }
  }
  dtraw[(size_t)rw * 64 + lane]       = a0;
  dtraw[((size_t)rw + 1) * 64 + lane] = a1;
  dtraw[((size_t)rw + 2) * 64 + lane] = a2;
  dtraw[((size_t)rw + 3) * 64 + lane] = a3;
}

// ---------------- asm LDS read helpers (opaque to alias analysis) ----------------
static __device__ inline unsigned ldsaddr(const void* p){
  return (unsigned)(size_t)(const __attribute__((address_space(3))) void*)p;
}
static __device__ inline floatx4 dsr128(unsigned a){
  floatx4 d;
  asm volatile("ds_read_b128 %0, %1" : "=v"(d) : "v"(a));
  return d;
}
static __device__ inline half8 as_h8(floatx4 f){
  union { floatx4 f; half8 h; } u; u.f = f; return u.h;
}

// ---------------- 256x256 MFMA GEMM core, 4-phase/K-tile (R7 local optimum) ----
// 8 waves (2M x 4N), per-wave 128x64 = 8x4 16x16 frags. BK=64.
// LDS: 2 buffers x [256][64] fp16 for A and B = 128 KiB (1 block/CU).
// T2 swizzle: 16B slot q of row r stored at q^(r&7); pre-swizzled global source
// (linear LDS dest, rule #21) + same XOR on every ds_read. 0 bank conflicts.
// ds_reads inline-asm (opaque to alias analysis -> no lgkmcnt drain before the
// same-phase global_load_lds); reads cross the raw s_barrier un-drained; each
// MFMA phase opens with s_waitcnt lgkmcnt(0) + sched_barrier(0) (rule #18).
// Verified: 329 us gemm1 (864 TF), MfmaUtil 38%.
template<int KD>
__device__ inline void gemm256_core(const unsigned short* __restrict__ A,
                                    const unsigned short* __restrict__ B,
                                    int row0, int col0,
                                    unsigned short* sA, unsigned short* sB,
                                    floatx4 (&acc)[8][4], int t){
  const int lane = t & 63, wid = t >> 6;
  const int wm = wid >> 2, wn = wid & 3;
  const int quad = lane >> 4, l16 = lane & 15;
  const int srow  = t >> 3;                    // 0..63: row within 64-row stage block
  const int sslot = (t & 7) ^ (srow & 7);      // pre-swizzled global 16B slot
  constexpr int NT = KD / 64;

  auto stageA = [&](int d, int half, int kt){
    unsigned short* dst = sA + d*256*64 + half*128*64;
    const unsigned short* src = A + (size_t)(row0 + half*128) * KD + kt*64;
#pragma unroll
    for (int i = 0; i < 2; i++)
      async_cp16(src + (size_t)(i*64 + srow) * KD + sslot*8,
                 dst + ((size_t)i*512 + t)*8);
  };
  auto stageB = [&](int d, int half, int kt){
    unsigned short* dst = sB + d*256*64 + half*128*64;
    const unsigned short* src = B + (size_t)(col0 + half*128) * KD + kt*64;
#pragma unroll
    for (int i = 0; i < 2; i++)
      async_cp16(src + (size_t)(i*64 + srow) * KD + sslot*8,
                 dst + ((size_t)i*512 + t)*8);
  };

  const unsigned sAbase = ldsaddr(sA), sBbase = ldsaddr(sB);
  floatx4 af[8][2], bf[4][2];
  auto rdA = [&](unsigned base, int fr, int ks) -> floatx4 {
    return dsr128(base + 2u*(unsigned)((fr*16 + l16)*64 + (((ks*4+quad)^(l16&7))*8)));
  };
  auto rdB = [&](unsigned base, int fc, int ks) -> floatx4 {
    return dsr128(base + 2u*(unsigned)((fc*16 + l16)*64 + (((ks*4+quad)^(l16&7))*8)));
  };
  auto mmac = [&](int mh, int nh){
    __builtin_amdgcn_s_setprio(1);
#pragma unroll
    for (int mm = 0; mm < 4; mm++)
#pragma unroll
      for (int nn = 0; nn < 2; nn++)
#pragma unroll
        for (int ks = 0; ks < 2; ks++)
          acc[mh*4+mm][nh*2+nn] = __builtin_amdgcn_mfma_f32_16x16x32_f16(
              as_h8(af[mh*4+mm][ks]), as_h8(bf[nh*2+nn][ks]), acc[mh*4+mm][nh*2+nn], 0, 0, 0);
    __builtin_amdgcn_s_setprio(0);
  };

  // prologue: tile0 full -> buf0 (8 loads), tile1 A -> buf1 (4 loads)
  stageA(0,0,0); stageA(0,1,0); stageB(0,0,0); stageB(0,1,0);
  stageA(1,0,1); stageA(1,1,1);
  asm volatile("s_waitcnt vmcnt(4)" ::: "memory");   // tile0's 8 loads landed
  __builtin_amdgcn_s_barrier();

  for (int T = 0; T < NT; T++){
    const int cur = T & 1;
    const unsigned aAd = sAbase + 2u*(unsigned)(cur*256*64 + wm*128*64);
    const unsigned bAd = sBbase + 2u*(unsigned)(cur*256*64 + wn*64*64);
    // ---------------- phase 0: read A0-3,B0-1 | stage B-top(T+1) ----------------
#pragma unroll
    for (int fr = 0; fr < 4; fr++)
#pragma unroll
      for (int ks = 0; ks < 2; ks++)
        af[fr][ks] = rdA(aAd, fr, ks);
#pragma unroll
    for (int fc = 0; fc < 2; fc++)
#pragma unroll
      for (int ks = 0; ks < 2; ks++)
        bf[fc][ks] = rdB(bAd, fc, ks);
    if (T + 1 < NT) stageB(cur^1, 0, T+1);
    __builtin_amdgcn_s_barrier();
    asm volatile("s_waitcnt lgkmcnt(0)" ::: "memory");
    __builtin_amdgcn_sched_barrier(0);
    mmac(0, 0);
    __builtin_amdgcn_s_barrier();
    // ---------------- phase 1: read A4-7 | stage B-bot(T+1) ----------------
#pragma unroll
    for (int fr = 4; fr < 8; fr++)
#pragma unroll
      for (int ks = 0; ks < 2; ks++)
        af[fr][ks] = rdA(aAd, fr, ks);
    if (T + 1 < NT) stageB(cur^1, 1, T+1);
    __builtin_amdgcn_s_barrier();
    asm volatile("s_waitcnt lgkmcnt(0)" ::: "memory");
    __builtin_amdgcn_sched_barrier(0);
    mmac(1, 0);
    __builtin_amdgcn_s_barrier();
    // ---------------- phase 2: read B2-3 ----------------
#pragma unroll
    for (int fc = 2; fc < 4; fc++)
#pragma unroll
      for (int ks = 0; ks < 2; ks++)
        bf[fc][ks] = rdB(bAd, fc, ks);
    __builtin_amdgcn_s_barrier();
    asm volatile("s_waitcnt lgkmcnt(0)" ::: "memory");
    __builtin_amdgcn_sched_barrier(0);
    mmac(0, 1);
    __builtin_amdgcn_s_barrier();
    // ---------------- phase 3: stage A(T+2), counted vmcnt ----------------
    if (T + 2 < NT){
      stageA(cur, 0, T+2); stageA(cur, 1, T+2);
      asm volatile("s_waitcnt vmcnt(4)" ::: "memory");
    } else if (T + 1 < NT){
      asm volatile("s_waitcnt vmcnt(0)" ::: "memory");
    }
    __builtin_amdgcn_s_barrier();
    mmac(1, 1);
    __builtin_amdgcn_s_barrier();
  }
}

// ---------------- GEMM1: routed fp16 epilogue (z | xs | bc) ----------------
__global__ __launch_bounds__(512, 2)
void k_gemm1(const unsigned short* __restrict__ A, const unsigned short* __restrict__ B,
             unsigned short* __restrict__ zbuf, unsigned short* __restrict__ xsraw,
             unsigned short* __restrict__ bcraw){
  __shared__ __align__(16) unsigned short sA[2*256*64];
  __shared__ __align__(16) unsigned short sB[2*256*64];
  const int t = threadIdx.x;
  // bijective XCD swizzle: 1056 = 8 * 132
  int swz = (blockIdx.x % 8) * 132 + blockIdx.x / 8;
  const int row0 = (swz & 31) * 256, col0 = (swz >> 5) * 256;
  floatx4 acc[8][4] = {};
  gemm256_core<DIMK>(A, B, row0, col0, sA, sB, acc, t);
  const int lane = t & 63, wid = t >> 6;
  const int wm = wid >> 2, wn = wid & 3;
  const int quad = lane >> 4, l16 = lane & 15;
  unsigned short* dst; int cbase, ldd;
  if (col0 < 4096){ dst = zbuf; cbase = 0; ldd = 4096; }
  else if (col0 < 8192){ dst = xsraw; cbase = 4096; ldd = 4096; }
  else { dst = bcraw; cbase = 8192; ldd = 256; }
#pragma unroll
  for (int m = 0; m < 8; m++)
#pragma unroll
    for (int n = 0; n < 4; n++){
      int rb = row0 + wm*128 + m*16 + quad*4;
      int cc = col0 + wn*64 + n*16 + l16 - cbase;
#pragma unroll
      for (int r = 0; r < 4; r++)
        dst[(size_t)(rb + r) * ldd + cc] = f2h(acc[m][n][r]);
    }
}

// ---------------- GEMM2: fp32 epilogue to d_out ----------------
__global__ __launch_bounds__(512, 2)
void k_gemm2(const unsigned short* __restrict__ A, const unsigned short* __restrict__ B,
             float* __restrict__ C){
  __shared__ __align__(16) unsigned short sA[2*256*64];
  __shared__ __align__(16) unsigned short sB[2*256*64];
  const int t = threadIdx.x;
  // bijective XCD swizzle: 256 = 8 * 32
  int swz = (blockIdx.x % 8) * 32 + blockIdx.x / 8;
  const int row0 = (swz & 31) * 256, col0 = (swz >> 5) * 256;
  floatx4 acc[8][4] = {};
  gemm256_core<HIDN>(A, B, row0, col0, sA, sB, acc, t);
  const int lane = t & 63, wid = t >> 6;
  const int wm = wid >> 2, wn = wid & 3;
  const int quad = lane >> 4, l16 = lane & 15;
#pragma unroll
  for (int m = 0; m < 8; m++)
#pragma unroll
    for (int n = 0; n < 4; n++){
      int rb = row0 + wm*128 + m*16 + quad*4;
      int cc = col0 + wn*64 + n*16 + l16;
#pragma unroll
      for (int r = 0; r < 4; r++)
        C[(size_t)(rb + r) * DIMK + cc] = acc[m][n][r];
    }
}

// ---------------- merged post-gemm1 small kernels ----------------
// [0,8192): causal conv K=4 + SiLU on B/C cols   (reads bcraw -> bcc)
// [8192,11264): extract pre-conv xs halo rows     (reads xsraw -> halo)
// [11264,11280): softplus(dt) + per-chunk cumsum  (reads dtraw -> dtb, cumb)
// Sub-parts mutually independent; each identical to its former standalone kernel.
__global__ void k_mid(const unsigned short* __restrict__ bcraw, const float* __restrict__ cw,
                      unsigned short* __restrict__ bcc,
                      const unsigned short* __restrict__ xsraw, unsigned short* __restrict__ halo,
                      const float* __restrict__ dtraw, const float* __restrict__ dtbias,
                      const float* __restrict__ Alog, float* __restrict__ dtb,
                      float* __restrict__ cumb){
  int blk = blockIdx.x, t = threadIdx.x;
  if (blk < 8192){
    int row = blk, c = t;
    int tl = row & 4095;
    const float4 wv = *(const float4*)&cw[(size_t)(4096 + c) * 4];
    const unsigned short* col = bcraw + c;
    size_t rb = (size_t)row * 256;
    float a = h2f(col[rb]) * wv.w;
    if (tl >= 1) a += h2f(col[rb - 256]) * wv.z;
    if (tl >= 2) a += h2f(col[rb - 512]) * wv.y;
    if (tl >= 3) a += h2f(col[rb - 768]) * wv.x;
    bcc[rb + c] = f2h(a / (1.f + __expf(-a)));
  } else if (blk < 11264){
    int idx = blk - 8192;                       // [0,3072) = 16 x 3 x 64
    int col = (idx & 15) * 256 + t;
    int slot = (idx >> 4) % 3;
    int bc = idx / 48;
    long r = (long)bc * QCH - 3 + slot;
    if (r >= 0)
      halo[((size_t)bc * 3 + slot) * 4096 + col] = xsraw[(size_t)r * 4096 + col];
  } else {
    int lb = blk - 11264;                       // [0,16): 4 chunks x 64 heads per block
    int bc = lb * 4 + (t >> 6);
    int h = t & 63;
    float bias = dtbias[h];
    float A = -__expf(Alog[h]);
    float run = 0.f;
    size_t rowb = (size_t)bc * QCH;
    for (int q = 0; q < QCH; q++){
      float dr = dtraw[(rowb + q) * 64 + h] + bias;
      float dt = dr > 20.f ? dr : log1pf(__expf(dr));
      dtb[(rowb + q) * 64 + h] = dt;
      run += dt * A;
      cumb[(rowb + q) * 64 + h] = run;
    }
  }
}

// ---------------- fused conv+SiLU staging of xs tile, transposed (P x Q) ----------------
// tap t-k, row rowb+q-k: in-chunk if q>=k, else halo slot (q-k+3)
__device__ inline void stage_xsT(const unsigned short* __restrict__ xsraw,
                                 const unsigned short* __restrict__ halo,
                                 const float* cws, unsigned short* xsT,
                                 int bc, int h, int t){
  const size_t rowb = (size_t)bc * QCH;
  const int tl0 = (bc & 31) * QCH;
#pragma unroll
  for (int it = 0; it < 2; it++){
    int idx = it * 256 + t;
    int q = idx & 127, p0 = (idx >> 7) * 16;
    int tl = tl0 + q;
    const unsigned short* cur = xsraw + (rowb + q) * 4096 + h * 64 + p0;
    const unsigned short* hb  = halo + ((size_t)bc * 3) * 4096 + h * 64 + p0;
    const unsigned short* r1 = (q >= 1) ? cur - 4096     : hb + 2 * 4096;
    const unsigned short* r2 = (q >= 2) ? cur - 2 * 4096 : hb + (size_t)(q + 1) * 4096;
    const unsigned short* r3 = (q >= 3) ? cur - 3 * 4096 : hb + (size_t)q * 4096;
    float f1 = (tl >= 1) ? 1.f : 0.f;
    float f2 = (tl >= 2) ? 1.f : 0.f;
    float f3 = (tl >= 3) ? 1.f : 0.f;
    short8 c0 = *(const short8*)cur, c1 = *(const short8*)(cur + 8);
    short8 a0 = *(const short8*)r1,  a1 = *(const short8*)(r1 + 8);
    short8 b0 = *(const short8*)r2,  b1 = *(const short8*)(r2 + 8);
    short8 d0 = *(const short8*)r3,  d1 = *(const short8*)(r3 + 8);
#pragma unroll
    for (int j = 0; j < 16; j++){
      int col = p0 + j;
      const float* wp = cws + col * 4;
      float vc = h2f((unsigned short)(j < 8 ? c0[j] : c1[j-8]));
      float v1 = h2f((unsigned short)(j < 8 ? a0[j] : a1[j-8]));
      float v2 = h2f((unsigned short)(j < 8 ? b0[j] : b1[j-8]));
      float v3 = h2f((unsigned short)(j < 8 ? d0[j] : d1[j-8]));
      float a = vc * wp[3] + f1 * v1 * wp[2] + f2 * v2 * wp[1] + f3 * v3 * wp[0];
      float s = a / (1.f + __expf(-a));
      xsT[col * 128 + q] = f2h(s);
    }
  }
}

// ---------------- per-(chunk,head): CB -> M -> Yd; + Yoff from Sprev; y = Yd+Yoff+D*xs ----------------
// xsc = POST-conv xs (chunk2 wrote it back in place over xsraw) in [row][col] layout.
__global__ __launch_bounds__(256, 2)
void k_chunk1(const unsigned short* __restrict__ xsc, const unsigned short* __restrict__ bcc,
              const float* __restrict__ dtb, const float* __restrict__ cumb,
              const float* __restrict__ Dp, const unsigned short* __restrict__ st,
              unsigned short* __restrict__ ybuf){
  __shared__ __align__(16) unsigned short Ml[128*128];
  __shared__ __align__(16) unsigned short xsT[64*128];
  __shared__ float cum_s[128], dt_s[128];
  const int blk = blockIdx.x, h = blk & 63, bc = blk >> 6;
  const size_t rowb = (size_t)bc * QCH;
  const int t = threadIdx.x, w = t >> 6, lane = t & 63, quad = lane >> 4, l16 = lane & 15;
  const int wrow = w * 32;
  if (t < 128){ cum_s[t] = cumb[(rowb + t)*64 + h]; dt_s[t] = dtb[(rowb + t)*64 + h]; }
  __syncthreads();
  // copy-transpose post-conv xs tile into xsT (no conv recompute)
#pragma unroll
  for (int it = 0; it < 2; it++){
    int idx = it * 256 + t;
    int q = idx & 127, p0 = (idx >> 7) * 16;
    const unsigned short* cur = xsc + (rowb + q) * 4096 + h * 64 + p0;
    short8 c0 = *(const short8*)cur, c1 = *(const short8*)(cur + 8);
#pragma unroll
    for (int j = 0; j < 16; j++)
      xsT[(p0 + j) * 128 + q] = (unsigned short)(j < 8 ? c0[j] : c1[j-8]);
  }
  // CB = C @ B^T from post-conv bcc
  floatx4 acc[2][8] = {};
  const unsigned short* Cb = bcc + rowb * 256 + 128;
  const unsigned short* Bb = bcc + rowb * 256;
#pragma unroll
  for (int ks = 0; ks < 4; ks++){
    half8 af[2];
#pragma unroll
    for (int i = 0; i < 2; i++)
      af[i] = *(const half8*)(Cb + (size_t)(wrow + i*16 + l16) * 256 + ks*32 + quad*8);
#pragma unroll
    for (int j = 0; j < 8; j++){
      half8 bfr = *(const half8*)(Bb + (size_t)(j*16 + l16) * 256 + ks*32 + quad*8);
#pragma unroll
      for (int i = 0; i < 2; i++)
        acc[i][j] = __builtin_amdgcn_mfma_f32_16x16x32_f16(af[i], bfr, acc[i][j], 0, 0, 0);
    }
  }
  // M = CB * exp(cum_i - cum_j) * dt_j, causal, -> LDS fp16
#pragma unroll
  for (int i = 0; i < 2; i++)
#pragma unroll
    for (int j = 0; j < 8; j++){
      int jc = j*16 + l16;
      float dtj = dt_s[jc], cj = cum_s[jc];
#pragma unroll
      for (int r = 0; r < 4; r++){
        int ir = wrow + i*16 + quad*4 + r;
        float m = (ir >= jc) ? acc[i][j][r] * __expf(cum_s[ir] - cj) * dtj : 0.f;
        Ml[ir * 128 + jc] = f2h(m);
      }
    }
  __syncthreads();
  // Yd = M @ xs
  floatx4 accY[2][4] = {};
#pragma unroll
  for (int ks = 0; ks < 4; ks++){
    half8 af[2], bfr[4];
#pragma unroll
    for (int i = 0; i < 2; i++)
      af[i] = *(const half8*)&Ml[(wrow + i*16 + l16)*128 + ks*32 + quad*8];
#pragma unroll
    for (int p = 0; p < 4; p++)
      bfr[p] = *(const half8*)&xsT[(p*16 + l16)*128 + ks*32 + quad*8];
#pragma unroll
    for (int i = 0; i < 2; i++)
#pragma unroll
      for (int p = 0; p < 4; p++)
        accY[i][p] = __builtin_amdgcn_mfma_f32_16x16x32_f16(af[i], bfr[p], accY[i][p], 0, 0, 0);
  }
  // ---- Yoff: stage Sprev (fp16) into Ml's LDS, then C @ Sprev^T ----
  __syncthreads();                       // all Yd reads of Ml done
  unsigned short* Sp = Ml;               // reuse (64*128 <= 128*128)
  {
    size_t base = ((size_t)bc * 64 + h) * 8192;
#pragma unroll
    for (int it = 0; it < 4; it++){
      int idx = (it * 256 + t) * 8;
      *(short8*)&Sp[idx] = *(const short8*)&st[base + idx];
    }
  }
  __syncthreads();
  floatx4 accO[2][4] = {};
#pragma unroll
  for (int ks = 0; ks < 4; ks++){
    half8 af[2], bfr[4];
#pragma unroll
    for (int i = 0; i < 2; i++)
      af[i] = *(const half8*)(Cb + (size_t)(wrow + i*16 + l16) * 256 + ks*32 + quad*8);
#pragma unroll
    for (int p = 0; p < 4; p++)
      bfr[p] = *(const half8*)&Sp[(p*16 + l16)*128 + ks*32 + quad*8];
#pragma unroll
    for (int i = 0; i < 2; i++)
#pragma unroll
      for (int p = 0; p < 4; p++)
        accO[i][p] = __builtin_amdgcn_mfma_f32_16x16x32_f16(af[i], bfr[p], accO[i][p], 0, 0, 0);
  }
  float Dh = Dp[h];
#pragma unroll
  for (int i = 0; i < 2; i++)
#pragma unroll
    for (int p = 0; p < 4; p++){
      int pc = p*16 + l16;
#pragma unroll
      for (int r = 0; r < 4; r++){
        int ir = wrow + i*16 + quad*4 + r;
        float y = accY[i][p][r] + __expf(cum_s[ir]) * accO[i][p][r] + Dh * h2f(xsT[pc*128 + ir]);
        ybuf[(rowb + ir) * (size_t)HIDN + h*64 + pc] = f2h(y);
      }
    }
}

// ---------------- per-(chunk,head): states[p][n] = sum_q xs[q][p]*wdec_q*B[q][n] ----------------
// Also writes POST-conv xs back over xsraw in place (consumed by k_chunk1).
__global__ __launch_bounds__(256, 2)
void k_chunk2(unsigned short* __restrict__ xsraw, const unsigned short* __restrict__ bcc,
              const unsigned short* __restrict__ halo, const float* __restrict__ cw,
              const float* __restrict__ dtb, const float* __restrict__ cumb,
              unsigned short* __restrict__ st){
  __shared__ __align__(16) unsigned short wBT[128*128];
  __shared__ __align__(16) unsigned short xsT[64*128];
  __shared__ float cum_s[128], dt_s[128];
  __shared__ float cws[64*4];
  const int blk = blockIdx.x, h = blk & 63, bc = blk >> 6;
  const size_t rowb = (size_t)bc * QCH;
  const int t = threadIdx.x, w = t >> 6, lane = t & 63, quad = lane >> 4, l16 = lane & 15;
  if (t < 128){ cum_s[t] = cumb[(rowb + t)*64 + h]; dt_s[t] = dtb[(rowb + t)*64 + h]; }
  if (t < 64) *(float4*)&cws[t*4] = *(const float4*)&cw[((size_t)h*64 + t)*4];
  __syncthreads();
  stage_xsT(xsraw, halo, cws, xsT, bc, h, t);
  __syncthreads();                 // all tap reads done before in-place overwrite
  // write post-conv xs back to global
#pragma unroll
  for (int it = 0; it < 2; it++){
    int idx = it * 256 + t;
    int q = idx & 127, p0 = (idx >> 7) * 16;
    short8 w0, w1;
#pragma unroll
    for (int j = 0; j < 8; j++){
      w0[j] = (short)xsT[(p0 + j) * 128 + q];
      w1[j] = (short)xsT[(p0 + 8 + j) * 128 + q];
    }
    unsigned short* g = xsraw + (rowb + q) * 4096 + h * 64 + p0;
    *(short8*)g = w0;
    *(short8*)(g + 8) = w1;
  }
  float clast = cum_s[127];
#pragma unroll
  for (int it = 0; it < 2; it++){                 // wBT[n][q] = B[q][n]*wdec_q
    int idx = it * 256 + t;
    int q = idx & 127, n0 = (idx >> 7) * 32;
    float wd = __expf(clast - cum_s[q]) * dt_s[q];
    const unsigned short* gp = bcc + (rowb + q) * 256 + n0;
#pragma unroll
    for (int c4 = 0; c4 < 4; c4++){
      short8 v = *(const short8*)(gp + c4*8);
#pragma unroll
      for (int jj = 0; jj < 8; jj++)
        wBT[(n0 + c4*8 + jj)*128 + q] = f2h(h2f((unsigned short)v[jj]) * wd);
    }
  }
  __syncthreads();
  floatx4 acc[8] = {};
#pragma unroll
  for (int ks = 0; ks < 4; ks++){
    half8 af = *(const half8*)&xsT[(w*16 + l16)*128 + ks*32 + quad*8];
#pragma unroll
    for (int j = 0; j < 8; j++){
      half8 bfr = *(const half8*)&wBT[(j*16 + l16)*128 + ks*32 + quad*8];
      acc[j] = __builtin_amdgcn_mfma_f32_16x16x32_f16(af, bfr, acc[j], 0, 0, 0);
    }
  }
  size_t base = ((size_t)bc * 64 + h) * 8192;
#pragma unroll
  for (int j = 0; j < 8; j++){
    int n = j*16 + l16;
#pragma unroll
    for (int r = 0; r < 4; r++){
      int p = w*16 + quad*4 + r;
      st[base + p*128 + n] = f2h(acc[j][r]);
    }
  }
}

// ---------------- sequential inter-chunk scan (fp16 states -> Sprev, in place) ----------------
// 2 adjacent n per thread (uint load/store); per-element arithmetic identical
// to the scalar version -> bit-identical output.
__global__ void k_scan(unsigned short* __restrict__ st, const float* __restrict__ cumb){
  int id = blockIdx.x * 256 + threadIdx.x;  // [0, 2*64*64*64)
  int n2 = id & 63, p = (id >> 6) & 63, h = (id >> 12) & 63, b = id >> 18;
  float S0 = 0.f, S1 = 0.f;
  for (int c = 0; c < NCHUNK; c++){
    int bc = b * NCHUNK + c;
    size_t idx = ((size_t)bc * 64 + h) * 8192 + (size_t)p * 128 + n2 * 2;
    float dec = __expf(cumb[((size_t)bc * QCH + 127) * 64 + h]);
    unsigned v = *(const unsigned*)&st[idx];
    float v0 = h2f((unsigned short)(v & 0xffff));
    float v1 = h2f((unsigned short)(v >> 16));
    unsigned o = (unsigned)f2h(S0) | ((unsigned)f2h(S1) << 16);
    *(unsigned*)&st[idx] = o;
    S0 = S0 * dec + v0;
    S1 = S1 * dec + v1;
  }
}

// ---------------- gate y*silu(z) + RMSNorm, in-place fp16 (vectorized) ----------
__global__ __launch_bounds__(256)
void k_gate(unsigned short* __restrict__ yb, const unsigned short* __restrict__ zb,
            const float* __restrict__ nw){
  __shared__ float red[4];
  int row = blockIdx.x, t = threadIdx.x;
  size_t base = (size_t)row * HIDN + t * 16;
  short8 y0 = *(const short8*)&yb[base], y1 = *(const short8*)&yb[base + 8];
  short8 z0 = *(const short8*)&zb[base], z1 = *(const short8*)&zb[base + 8];
  float vals[16], ss = 0.f;
#pragma unroll
  for (int j = 0; j < 8; j++){
    float y = h2f((unsigned short)y0[j]);
    float z = h2f((unsigned short)z0[j]);
    float v = y * (z / (1.f + __expf(-z)));
    vals[j] = v; ss += v * v;
  }
#pragma unroll
  for (int j = 0; j < 8; j++){
    float y = h2f((unsigned short)y1[j]);
    float z = h2f((unsigned short)z1[j]);
    float v = y * (z / (1.f + __expf(-z)));
    vals[8 + j] = v; ss += v * v;
  }
  for (int o = 32; o > 0; o >>= 1) ss += __shfl_down(ss, o, 64);
  int w = t >> 6, lane = t & 63;
  if (lane == 0) red[w] = ss;
  __syncthreads();
  float scale = rsqrtf((red[0] + red[1] + red[2] + red[3]) / (float)HIDN + 1e-5f);
  const float4 nw0 = *(const float4*)&nw[t*16];
  const float4 nw1 = *(const float4*)&nw[t*16 + 4];
  const float4 nw2 = *(const float4*)&nw[t*16 + 8];
  const float4 nw3 = *(const float4*)&nw[t*16 + 12];
  float nwv[16] = { nw0.x, nw0.y, nw0.z, nw0.w, nw1.x, nw1.y, nw1.z, nw1.w,
                    nw2.x, nw2.y, nw2.z, nw2.w, nw3.x, nw3.y, nw3.z, nw3.w };
  short8 o0, o1;
#pragma unroll
  for (int j = 0; j < 8; j++){
    o0[j] = (short)f2h(vals[j] * scale * nwv[j]);
    o1[j] = (short)f2h(vals[8 + j] * scale * nwv[8 + j]);
  }
  *(short8*)&yb[base]     = o0;
  *(short8*)&yb[base + 8] = o1;
}

extern "C" void kernel_launch(void* const* d_in, const int* in_sizes, int n_in,
                              void* d_out, int out_size, void* d_ws, size_t ws_size,
                              hipStream_t stream){
  const float* x      = (const float*)d_in[0];
  const float* Win    = (const float*)d_in[1];
  const float* convw  = (const float*)d_in[2];
  const float* dtbias = (const float*)d_in[3];
  const float* Alog   = (const float*)d_in[4];
  const float* Dp     = (const float*)d_in[5];
  const float* nw     = (const float*)d_in[6];
  const float* Wout   = (const float*)d_in[7];
  float* out = (float*)d_out;

  char* ws = (char*)d_ws;
  size_t off = 0;
  auto alloc = [&](size_t bytes)->void*{ void* p = ws + off; off += (bytes + 255) & ~(size_t)255; return p; };
  unsigned short* xw    = (unsigned short*)alloc((size_t)ROWS * DIMK * 2);   // 33.5 MB (dead after gemm1)
  unsigned short* winb  = (unsigned short*)alloc((size_t)8448 * DIMK * 2);   // 34.6 MB (dead after gemm1)
  float*          dtraw = (float*)alloc((size_t)ROWS * 64 * 4);              // 2.1 MB
  unsigned short* woutb = (unsigned short*)alloc((size_t)DIMK * HIDN * 2);   // 16.8 MB
  unsigned short* zbuf  = (unsigned short*)alloc((size_t)ROWS * HIDN * 2);   // 67.1 MB
  unsigned short* xsraw = (unsigned short*)alloc((size_t)ROWS * HIDN * 2);   // 67.1 MB (pre-conv xs -> post-conv xs -> y)
  unsigned short* bcraw = (unsigned short*)alloc((size_t)ROWS * 256 * 2);    // 4.2 MB
  unsigned short* bcc   = (unsigned short*)alloc((size_t)ROWS * 256 * 2);    // 4.2 MB
  unsigned short* halo  = (unsigned short*)alloc((size_t)64 * 3 * 4096 * 2); // 1.5 MB
  float*          dtb   = (float*)alloc((size_t)ROWS * 64 * 4);              // 2.1 MB
  float*          cumb  = (float*)alloc((size_t)ROWS * 64 * 4);              // 2.1 MB
  // total ~224.5 MiB; states (fp16, 67.1 MB) overlays dead xw+winb region
  unsigned short* st    = xw;
  unsigned short* ybuf  = xsraw;   // chunk1 writes y in-place over post-conv xs

  k_prep<<<41472, 256, 0, stream>>>(x, Win, Wout, xw, winb, woutb);
  k_dtraw<<<ROWS/16, 256, 0, stream>>>(x, Win, dtraw);
  k_gemm1<<<dim3(33*32), 512, 0, stream>>>(xw, winb, zbuf, xsraw, bcraw);
  k_mid<<<11280, 256, 0, stream>>>(bcraw, convw, bcc, xsraw, halo,
                                   dtraw, dtbias, Alog, dtb, cumb);
  k_chunk2<<<4096, 256, 0, stream>>>(xsraw, bcc, halo, convw, dtb, cumb, st);
  k_scan<<<2048, 256, 0, stream>>>(st, cumb);
  k_chunk1<<<4096, 256, 0, stream>>>(xsraw, bcc, dtb, cumb, Dp, st, ybuf);
  k_gate<<<ROWS, 256, 0, stream>>>(ybuf, zbuf, nw);
  k_gemm2<<<dim3(8*32), 512, 0, stream>>>(ybuf, woutb, out);
}

// Round 11
// 1048.898 us; speedup vs baseline: 1.1802x; 1.0327x over previous
//
#include <hip/hip_runtime.h>
#include <hip/hip_fp16.h>
#include <math.h>

// Problem constants
#define ROWS   8192        // B*L = 2*4096
#define DIMK   2048
#define HIDN   4096
#define QCH    128
#define NCHUNK 32          // L/Q per batch
#define CST    136         // chunk-kernel LDS row stride (shorts): 272B = 68 dwords,
                           // 68r mod 32 = 4r -> 16-row MFMA reads are 2-way (free)
                           // vs 128-stride's 16-way conflict (5.69x, m136)

typedef __attribute__((ext_vector_type(8))) short short8;
typedef __attribute__((ext_vector_type(8))) _Float16 half8;
typedef __attribute__((ext_vector_type(4))) float floatx4;

static __device__ inline unsigned short f2h(float f){
  union { _Float16 h; unsigned short u; } v; v.h = (_Float16)f; return v.u;
}
static __device__ inline float h2f(unsigned short u){
  union { unsigned short u; _Float16 h; } v; v.u = u; return (float)v.h;
}
static __device__ inline void async_cp16(const void* g, void* l){
  __builtin_amdgcn_global_load_lds((const __attribute__((address_space(1))) void*)g,
                                   (__attribute__((address_space(3))) void*)l, 16, 0, 0);
}

// ---------------- merged fp32 -> fp16 cast for x, W_in[0:8448], W_out ----------
__global__ void k_prep(const float* __restrict__ x, const float* __restrict__ Win,
                       const float* __restrict__ Wout, unsigned short* __restrict__ xw,
                       unsigned short* __restrict__ winb, unsigned short* __restrict__ woutb){
  int blk = blockIdx.x, t = threadIdx.x;
  const float* src; unsigned short* dst; int i;
  if (blk < 16384){ src = x;    dst = xw;    i = blk * 256 + t; }
  else if (blk < 33280){ src = Win;  dst = winb;  i = (blk - 16384) * 256 + t; }
  else { src = Wout; dst = woutb; i = (blk - 33280) * 256 + t; }
  float4 v = ((const float4*)src)[i];
  unsigned long long p = (unsigned long long)f2h(v.x)
                       | ((unsigned long long)f2h(v.y) << 16)
                       | ((unsigned long long)f2h(v.z) << 32)
                       | ((unsigned long long)f2h(v.w) << 48);
  ((unsigned long long*)dst)[i] = p;
}

// ---------------- exact fp32 dt_raw = x @ W_in[8448:8512].T ----------------
__global__ __launch_bounds__(256)
void k_dtraw(const float* __restrict__ x, const float* __restrict__ Win,
             float* __restrict__ dtraw){
  __shared__ float ws[64 * 132];
  const int t = threadIdx.x;
  const int lane = t & 63, w = t >> 6;
  const int r0 = blockIdx.x * 16;
  const int rw = __builtin_amdgcn_readfirstlane(r0 + w * 4);
  float a0 = 0.f, a1 = 0.f, a2 = 0.f, a3 = 0.f;
  for (int k0 = 0; k0 < DIMK; k0 += 128){
    __syncthreads();                              // previous tile's reads done
#pragma unroll
    for (int l = 0; l < 8; l++){
      int fidx = (l * 256 + t) * 4;               // 0..8191 floats
      int row = fidx >> 7, col = fidx & 127;
      *(float4*)&ws[row * 132 + col] =
          *(const float4*)&Win[(size_t)(8448 + row) * DIMK + k0 + col];
    }
    __syncthreads();
    const float* xp = x + (size_t)rw * DIMK + k0;
#pragma unroll 8
    for (int kk = 0; kk < 128; kk += 4){
      float4 wv = *(const float4*)&ws[lane * 132 + kk];
      float4 v0 = *(const float4*)&xp[kk];
      float4 v1 = *(const float4*)&xp[DIMK + kk];
      float4 v2 = *(const float4*)&xp[2*DIMK + kk];
      float4 v3 = *(const float4*)&xp[3*DIMK + kk];
      a0 += wv.x*v0.x + wv.y*v0.y + wv.z*v0.z + wv.w*v0.w;
      a1 += wv.x*v1.x + wv.y*v1.y + wv.z*v1.z + wv.w*v1.w;
      a2 += wv.x*v2.x + wv.y*v2.y + wv.z*v2.z + wv.w*v2.w;
      a3 += wv.x*v3.x + wv.y*v3.y + wv.z*v3.z + wv.w*v3.w;
    }
  }
  dtraw[(size_t)rw * 64 + lane]       = a0;
  dtraw[((size_t)rw + 1) * 64 + lane] = a1;
  dtraw[((size_t)rw + 2) * 64 + lane] = a2;
  dtraw[((size_t)rw + 3) * 64 + lane] = a3;
}

// ---------------- asm LDS read helpers (opaque to alias analysis) ----------------
static __device__ inline unsigned ldsaddr(const void* p){
  return (unsigned)(size_t)(const __attribute__((address_space(3))) void*)p;
}
static __device__ inline floatx4 dsr128(unsigned a){
  floatx4 d;
  asm volatile("ds_read_b128 %0, %1" : "=v"(d) : "v"(a));
  return d;
}
static __device__ inline half8 as_h8(floatx4 f){
  union { floatx4 f; half8 h; } u; u.f = f; return u.h;
}

// ---------------- 256x256 MFMA GEMM core, 4-phase/K-tile (R7 local optimum) ----
template<int KD>
__device__ inline void gemm256_core(const unsigned short* __restrict__ A,
                                    const unsigned short* __restrict__ B,
                                    int row0, int col0,
                                    unsigned short* sA, unsigned short* sB,
                                    floatx4 (&acc)[8][4], int t){
  const int lane = t & 63, wid = t >> 6;
  const int wm = wid >> 2, wn = wid & 3;
  const int quad = lane >> 4, l16 = lane & 15;
  const int srow  = t >> 3;                    // 0..63: row within 64-row stage block
  const int sslot = (t & 7) ^ (srow & 7);      // pre-swizzled global 16B slot
  constexpr int NT = KD / 64;

  auto stageA = [&](int d, int half, int kt){
    unsigned short* dst = sA + d*256*64 + half*128*64;
    const unsigned short* src = A + (size_t)(row0 + half*128) * KD + kt*64;
#pragma unroll
    for (int i = 0; i < 2; i++)
      async_cp16(src + (size_t)(i*64 + srow) * KD + sslot*8,
                 dst + ((size_t)i*512 + t)*8);
  };
  auto stageB = [&](int d, int half, int kt){
    unsigned short* dst = sB + d*256*64 + half*128*64;
    const unsigned short* src = B + (size_t)(col0 + half*128) * KD + kt*64;
#pragma unroll
    for (int i = 0; i < 2; i++)
      async_cp16(src + (size_t)(i*64 + srow) * KD + sslot*8,
                 dst + ((size_t)i*512 + t)*8);
  };

  const unsigned sAbase = ldsaddr(sA), sBbase = ldsaddr(sB);
  floatx4 af[8][2], bf[4][2];
  auto rdA = [&](unsigned base, int fr, int ks) -> floatx4 {
    return dsr128(base + 2u*(unsigned)((fr*16 + l16)*64 + (((ks*4+quad)^(l16&7))*8)));
  };
  auto rdB = [&](unsigned base, int fc, int ks) -> floatx4 {
    return dsr128(base + 2u*(unsigned)((fc*16 + l16)*64 + (((ks*4+quad)^(l16&7))*8)));
  };
  auto mmac = [&](int mh, int nh){
    __builtin_amdgcn_s_setprio(1);
#pragma unroll
    for (int mm = 0; mm < 4; mm++)
#pragma unroll
      for (int nn = 0; nn < 2; nn++)
#pragma unroll
        for (int ks = 0; ks < 2; ks++)
          acc[mh*4+mm][nh*2+nn] = __builtin_amdgcn_mfma_f32_16x16x32_f16(
              as_h8(af[mh*4+mm][ks]), as_h8(bf[nh*2+nn][ks]), acc[mh*4+mm][nh*2+nn], 0, 0, 0);
    __builtin_amdgcn_s_setprio(0);
  };

  // prologue: tile0 full -> buf0 (8 loads), tile1 A -> buf1 (4 loads)
  stageA(0,0,0); stageA(0,1,0); stageB(0,0,0); stageB(0,1,0);
  stageA(1,0,1); stageA(1,1,1);
  asm volatile("s_waitcnt vmcnt(4)" ::: "memory");   // tile0's 8 loads landed
  __builtin_amdgcn_s_barrier();

  for (int T = 0; T < NT; T++){
    const int cur = T & 1;
    const unsigned aAd = sAbase + 2u*(unsigned)(cur*256*64 + wm*128*64);
    const unsigned bAd = sBbase + 2u*(unsigned)(cur*256*64 + wn*64*64);
    // ---------------- phase 0: read A0-3,B0-1 | stage B-top(T+1) ----------------
#pragma unroll
    for (int fr = 0; fr < 4; fr++)
#pragma unroll
      for (int ks = 0; ks < 2; ks++)
        af[fr][ks] = rdA(aAd, fr, ks);
#pragma unroll
    for (int fc = 0; fc < 2; fc++)
#pragma unroll
      for (int ks = 0; ks < 2; ks++)
        bf[fc][ks] = rdB(bAd, fc, ks);
    if (T + 1 < NT) stageB(cur^1, 0, T+1);
    __builtin_amdgcn_s_barrier();
    asm volatile("s_waitcnt lgkmcnt(0)" ::: "memory");
    __builtin_amdgcn_sched_barrier(0);
    mmac(0, 0);
    __builtin_amdgcn_s_barrier();
    // ---------------- phase 1: read A4-7 | stage B-bot(T+1) ----------------
#pragma unroll
    for (int fr = 4; fr < 8; fr++)
#pragma unroll
      for (int ks = 0; ks < 2; ks++)
        af[fr][ks] = rdA(aAd, fr, ks);
    if (T + 1 < NT) stageB(cur^1, 1, T+1);
    __builtin_amdgcn_s_barrier();
    asm volatile("s_waitcnt lgkmcnt(0)" ::: "memory");
    __builtin_amdgcn_sched_barrier(0);
    mmac(1, 0);
    __builtin_amdgcn_s_barrier();
    // ---------------- phase 2: read B2-3 ----------------
#pragma unroll
    for (int fc = 2; fc < 4; fc++)
#pragma unroll
      for (int ks = 0; ks < 2; ks++)
        bf[fc][ks] = rdB(bAd, fc, ks);
    __builtin_amdgcn_s_barrier();
    asm volatile("s_waitcnt lgkmcnt(0)" ::: "memory");
    __builtin_amdgcn_sched_barrier(0);
    mmac(0, 1);
    __builtin_amdgcn_s_barrier();
    // ---------------- phase 3: stage A(T+2), counted vmcnt ----------------
    if (T + 2 < NT){
      stageA(cur, 0, T+2); stageA(cur, 1, T+2);
      asm volatile("s_waitcnt vmcnt(4)" ::: "memory");
    } else if (T + 1 < NT){
      asm volatile("s_waitcnt vmcnt(0)" ::: "memory");
    }
    __builtin_amdgcn_s_barrier();
    mmac(1, 1);
    __builtin_amdgcn_s_barrier();
  }
}

// ---------------- GEMM1: routed fp16 epilogue (z | xs | bc) ----------------
__global__ __launch_bounds__(512, 2)
void k_gemm1(const unsigned short* __restrict__ A, const unsigned short* __restrict__ B,
             unsigned short* __restrict__ zbuf, unsigned short* __restrict__ xsraw,
             unsigned short* __restrict__ bcraw){
  __shared__ __align__(16) unsigned short sA[2*256*64];
  __shared__ __align__(16) unsigned short sB[2*256*64];
  const int t = threadIdx.x;
  // bijective XCD swizzle: 1056 = 8 * 132
  int swz = (blockIdx.x % 8) * 132 + blockIdx.x / 8;
  const int row0 = (swz & 31) * 256, col0 = (swz >> 5) * 256;
  floatx4 acc[8][4] = {};
  gemm256_core<DIMK>(A, B, row0, col0, sA, sB, acc, t);
  const int lane = t & 63, wid = t >> 6;
  const int wm = wid >> 2, wn = wid & 3;
  const int quad = lane >> 4, l16 = lane & 15;
  unsigned short* dst; int cbase, ldd;
  if (col0 < 4096){ dst = zbuf; cbase = 0; ldd = 4096; }
  else if (col0 < 8192){ dst = xsraw; cbase = 4096; ldd = 4096; }
  else { dst = bcraw; cbase = 8192; ldd = 256; }
#pragma unroll
  for (int m = 0; m < 8; m++)
#pragma unroll
    for (int n = 0; n < 4; n++){
      int rb = row0 + wm*128 + m*16 + quad*4;
      int cc = col0 + wn*64 + n*16 + l16 - cbase;
#pragma unroll
      for (int r = 0; r < 4; r++)
        dst[(size_t)(rb + r) * ldd + cc] = f2h(acc[m][n][r]);
    }
}

// ---------------- GEMM2: fp32 epilogue to d_out ----------------
__global__ __launch_bounds__(512, 2)
void k_gemm2(const unsigned short* __restrict__ A, const unsigned short* __restrict__ B,
             float* __restrict__ C){
  __shared__ __align__(16) unsigned short sA[2*256*64];
  __shared__ __align__(16) unsigned short sB[2*256*64];
  const int t = threadIdx.x;
  // bijective XCD swizzle: 256 = 8 * 32
  int swz = (blockIdx.x % 8) * 32 + blockIdx.x / 8;
  const int row0 = (swz & 31) * 256, col0 = (swz >> 5) * 256;
  floatx4 acc[8][4] = {};
  gemm256_core<HIDN>(A, B, row0, col0, sA, sB, acc, t);
  const int lane = t & 63, wid = t >> 6;
  const int wm = wid >> 2, wn = wid & 3;
  const int quad = lane >> 4, l16 = lane & 15;
#pragma unroll
  for (int m = 0; m < 8; m++)
#pragma unroll
    for (int n = 0; n < 4; n++){
      int rb = row0 + wm*128 + m*16 + quad*4;
      int cc = col0 + wn*64 + n*16 + l16;
#pragma unroll
      for (int r = 0; r < 4; r++)
        C[(size_t)(rb + r) * DIMK + cc] = acc[m][n][r];
    }
}

// ---------------- merged post-gemm1 small kernels ----------------
__global__ void k_mid(const unsigned short* __restrict__ bcraw, const float* __restrict__ cw,
                      unsigned short* __restrict__ bcc,
                      const unsigned short* __restrict__ xsraw, unsigned short* __restrict__ halo,
                      const float* __restrict__ dtraw, const float* __restrict__ dtbias,
                      const float* __restrict__ Alog, float* __restrict__ dtb,
                      float* __restrict__ cumb){
  int blk = blockIdx.x, t = threadIdx.x;
  if (blk < 8192){
    int row = blk, c = t;
    int tl = row & 4095;
    const float4 wv = *(const float4*)&cw[(size_t)(4096 + c) * 4];
    const unsigned short* col = bcraw + c;
    size_t rb = (size_t)row * 256;
    float a = h2f(col[rb]) * wv.w;
    if (tl >= 1) a += h2f(col[rb - 256]) * wv.z;
    if (tl >= 2) a += h2f(col[rb - 512]) * wv.y;
    if (tl >= 3) a += h2f(col[rb - 768]) * wv.x;
    bcc[rb + c] = f2h(a / (1.f + __expf(-a)));
  } else if (blk < 11264){
    int idx = blk - 8192;                       // [0,3072) = 16 x 3 x 64
    int col = (idx & 15) * 256 + t;
    int slot = (idx >> 4) % 3;
    int bc = idx / 48;
    long r = (long)bc * QCH - 3 + slot;
    if (r >= 0)
      halo[((size_t)bc * 3 + slot) * 4096 + col] = xsraw[(size_t)r * 4096 + col];
  } else {
    int lb = blk - 11264;                       // [0,16): 4 chunks x 64 heads per block
    int bc = lb * 4 + (t >> 6);
    int h = t & 63;
    float bias = dtbias[h];
    float A = -__expf(Alog[h]);
    float run = 0.f;
    size_t rowb = (size_t)bc * QCH;
    for (int q = 0; q < QCH; q++){
      float dr = dtraw[(rowb + q) * 64 + h] + bias;
      float dt = dr > 20.f ? dr : log1pf(__expf(dr));
      dtb[(rowb + q) * 64 + h] = dt;
      run += dt * A;
      cumb[(rowb + q) * 64 + h] = run;
    }
  }
}

// ---------------- fused conv+SiLU staging of xs tile, transposed (P x Q) ----------------
// writes xsT with row stride CST (conflict-free MFMA reads)
__device__ inline void stage_xsT(const unsigned short* __restrict__ xsraw,
                                 const unsigned short* __restrict__ halo,
                                 const float* cws, unsigned short* xsT,
                                 int bc, int h, int t){
  const size_t rowb = (size_t)bc * QCH;
  const int tl0 = (bc & 31) * QCH;
#pragma unroll
  for (int it = 0; it < 2; it++){
    int idx = it * 256 + t;
    int q = idx & 127, p0 = (idx >> 7) * 16;
    int tl = tl0 + q;
    const unsigned short* cur = xsraw + (rowb + q) * 4096 + h * 64 + p0;
    const unsigned short* hb  = halo + ((size_t)bc * 3) * 4096 + h * 64 + p0;
    const unsigned short* r1 = (q >= 1) ? cur - 4096     : hb + 2 * 4096;
    const unsigned short* r2 = (q >= 2) ? cur - 2 * 4096 : hb + (size_t)(q + 1) * 4096;
    const unsigned short* r3 = (q >= 3) ? cur - 3 * 4096 : hb + (size_t)q * 4096;
    float f1 = (tl >= 1) ? 1.f : 0.f;
    float f2 = (tl >= 2) ? 1.f : 0.f;
    float f3 = (tl >= 3) ? 1.f : 0.f;
    short8 c0 = *(const short8*)cur, c1 = *(const short8*)(cur + 8);
    short8 a0 = *(const short8*)r1,  a1 = *(const short8*)(r1 + 8);
    short8 b0 = *(const short8*)r2,  b1 = *(const short8*)(r2 + 8);
    short8 d0 = *(const short8*)r3,  d1 = *(const short8*)(r3 + 8);
#pragma unroll
    for (int j = 0; j < 16; j++){
      int col = p0 + j;
      const float* wp = cws + col * 4;
      float vc = h2f((unsigned short)(j < 8 ? c0[j] : c1[j-8]));
      float v1 = h2f((unsigned short)(j < 8 ? a0[j] : a1[j-8]));
      float v2 = h2f((unsigned short)(j < 8 ? b0[j] : b1[j-8]));
      float v3 = h2f((unsigned short)(j < 8 ? d0[j] : d1[j-8]));
      float a = vc * wp[3] + f1 * v1 * wp[2] + f2 * v2 * wp[1] + f3 * v3 * wp[0];
      float s = a / (1.f + __expf(-a));
      xsT[col * CST + q] = f2h(s);
    }
  }
}

// ---------------- per-(chunk,head): CB -> M -> Yd; + Yoff from Sprev; y = Yd+Yoff+D*xs ----------------
// xsc = POST-conv xs (chunk2 wrote it back in place over xsraw) in [row][col] layout.
__global__ __launch_bounds__(256, 2)
void k_chunk1(const unsigned short* __restrict__ xsc, const unsigned short* __restrict__ bcc,
              const float* __restrict__ dtb, const float* __restrict__ cumb,
              const float* __restrict__ Dp, const unsigned short* __restrict__ st,
              unsigned short* __restrict__ ybuf){
  __shared__ __align__(16) unsigned short Ml[128*CST];
  __shared__ __align__(16) unsigned short xsT[64*CST];
  __shared__ float cum_s[128], dt_s[128];
  const int blk = blockIdx.x, h = blk & 63, bc = blk >> 6;
  const size_t rowb = (size_t)bc * QCH;
  const int t = threadIdx.x, w = t >> 6, lane = t & 63, quad = lane >> 4, l16 = lane & 15;
  const int wrow = w * 32;
  if (t < 128){ cum_s[t] = cumb[(rowb + t)*64 + h]; dt_s[t] = dtb[(rowb + t)*64 + h]; }
  __syncthreads();
  // copy-transpose post-conv xs tile into xsT (no conv recompute)
#pragma unroll
  for (int it = 0; it < 2; it++){
    int idx = it * 256 + t;
    int q = idx & 127, p0 = (idx >> 7) * 16;
    const unsigned short* cur = xsc + (rowb + q) * 4096 + h * 64 + p0;
    short8 c0 = *(const short8*)cur, c1 = *(const short8*)(cur + 8);
#pragma unroll
    for (int j = 0; j < 16; j++)
      xsT[(p0 + j) * CST + q] = (unsigned short)(j < 8 ? c0[j] : c1[j-8]);
  }
  // CB = C @ B^T from post-conv bcc
  floatx4 acc[2][8] = {};
  const unsigned short* Cb = bcc + rowb * 256 + 128;
  const unsigned short* Bb = bcc + rowb * 256;
#pragma unroll
  for (int ks = 0; ks < 4; ks++){
    half8 af[2];
#pragma unroll
    for (int i = 0; i < 2; i++)
      af[i] = *(const half8*)(Cb + (size_t)(wrow + i*16 + l16) * 256 + ks*32 + quad*8);
#pragma unroll
    for (int j = 0; j < 8; j++){
      half8 bfr = *(const half8*)(Bb + (size_t)(j*16 + l16) * 256 + ks*32 + quad*8);
#pragma unroll
      for (int i = 0; i < 2; i++)
        acc[i][j] = __builtin_amdgcn_mfma_f32_16x16x32_f16(af[i], bfr, acc[i][j], 0, 0, 0);
    }
  }
  // M = CB * exp(cum_i - cum_j) * dt_j, causal, -> LDS fp16
#pragma unroll
  for (int i = 0; i < 2; i++)
#pragma unroll
    for (int j = 0; j < 8; j++){
      int jc = j*16 + l16;
      float dtj = dt_s[jc], cj = cum_s[jc];
#pragma unroll
      for (int r = 0; r < 4; r++){
        int ir = wrow + i*16 + quad*4 + r;
        float m = (ir >= jc) ? acc[i][j][r] * __expf(cum_s[ir] - cj) * dtj : 0.f;
        Ml[ir * CST + jc] = f2h(m);
      }
    }
  __syncthreads();
  // Yd = M @ xs
  floatx4 accY[2][4] = {};
#pragma unroll
  for (int ks = 0; ks < 4; ks++){
    half8 af[2], bfr[4];
#pragma unroll
    for (int i = 0; i < 2; i++)
      af[i] = *(const half8*)&Ml[(wrow + i*16 + l16)*CST + ks*32 + quad*8];
#pragma unroll
    for (int p = 0; p < 4; p++)
      bfr[p] = *(const half8*)&xsT[(p*16 + l16)*CST + ks*32 + quad*8];
#pragma unroll
    for (int i = 0; i < 2; i++)
#pragma unroll
      for (int p = 0; p < 4; p++)
        accY[i][p] = __builtin_amdgcn_mfma_f32_16x16x32_f16(af[i], bfr[p], accY[i][p], 0, 0, 0);
  }
  // ---- Yoff: stage Sprev (fp16) into Ml's LDS (stride CST), then C @ Sprev^T ----
  __syncthreads();                       // all Yd reads of Ml done
  unsigned short* Sp = Ml;               // reuse (64*CST <= 128*CST)
  {
    size_t base = ((size_t)bc * 64 + h) * 8192;
#pragma unroll
    for (int it = 0; it < 4; it++){
      int flat = it * 256 + t;           // [0,1024): 64 rows x 16 copies of 8
      int row = flat >> 4, col = (flat & 15) * 8;
      *(short8*)&Sp[row * CST + col] = *(const short8*)&st[base + (size_t)row * 128 + col];
    }
  }
  __syncthreads();
  floatx4 accO[2][4] = {};
#pragma unroll
  for (int ks = 0; ks < 4; ks++){
    half8 af[2], bfr[4];
#pragma unroll
    for (int i = 0; i < 2; i++)
      af[i] = *(const half8*)(Cb + (size_t)(wrow + i*16 + l16) * 256 + ks*32 + quad*8);
#pragma unroll
    for (int p = 0; p < 4; p++)
      bfr[p] = *(const half8*)&Sp[(p*16 + l16)*CST + ks*32 + quad*8];
#pragma unroll
    for (int i = 0; i < 2; i++)
#pragma unroll
      for (int p = 0; p < 4; p++)
        accO[i][p] = __builtin_amdgcn_mfma_f32_16x16x32_f16(af[i], bfr[p], accO[i][p], 0, 0, 0);
  }
  float Dh = Dp[h];
#pragma unroll
  for (int i = 0; i < 2; i++)
#pragma unroll
    for (int p = 0; p < 4; p++){
      int pc = p*16 + l16;
#pragma unroll
      for (int r = 0; r < 4; r++){
        int ir = wrow + i*16 + quad*4 + r;
        float y = accY[i][p][r] + __expf(cum_s[ir]) * accO[i][p][r] + Dh * h2f(xsT[pc*CST + ir]);
        ybuf[(rowb + ir) * (size_t)HIDN + h*64 + pc] = f2h(y);
      }
    }
}

// ---------------- per-(chunk,head): states[p][n] = sum_q xs[q][p]*wdec_q*B[q][n] ----------------
// Also writes POST-conv xs back over xsraw in place (consumed by k_chunk1).
__global__ __launch_bounds__(256, 2)
void k_chunk2(unsigned short* __restrict__ xsraw, const unsigned short* __restrict__ bcc,
              const unsigned short* __restrict__ halo, const float* __restrict__ cw,
              const float* __restrict__ dtb, const float* __restrict__ cumb,
              unsigned short* __restrict__ st){
  __shared__ __align__(16) unsigned short wBT[128*CST];
  __shared__ __align__(16) unsigned short xsT[64*CST];
  __shared__ float cum_s[128], dt_s[128];
  __shared__ float cws[64*4];
  const int blk = blockIdx.x, h = blk & 63, bc = blk >> 6;
  const size_t rowb = (size_t)bc * QCH;
  const int t = threadIdx.x, w = t >> 6, lane = t & 63, quad = lane >> 4, l16 = lane & 15;
  if (t < 128){ cum_s[t] = cumb[(rowb + t)*64 + h]; dt_s[t] = dtb[(rowb + t)*64 + h]; }
  if (t < 64) *(float4*)&cws[t*4] = *(const float4*)&cw[((size_t)h*64 + t)*4];
  __syncthreads();
  stage_xsT(xsraw, halo, cws, xsT, bc, h, t);
  __syncthreads();                 // all tap reads done before in-place overwrite
  // write post-conv xs back to global
#pragma unroll
  for (int it = 0; it < 2; it++){
    int idx = it * 256 + t;
    int q = idx & 127, p0 = (idx >> 7) * 16;
    short8 w0, w1;
#pragma unroll
    for (int j = 0; j < 8; j++){
      w0[j] = (short)xsT[(p0 + j) * CST + q];
      w1[j] = (short)xsT[(p0 + 8 + j) * CST + q];
    }
    unsigned short* g = xsraw + (rowb + q) * 4096 + h * 64 + p0;
    *(short8*)g = w0;
    *(short8*)(g + 8) = w1;
  }
  float clast = cum_s[127];
#pragma unroll
  for (int it = 0; it < 2; it++){                 // wBT[n][q] = B[q][n]*wdec_q
    int idx = it * 256 + t;
    int q = idx & 127, n0 = (idx >> 7) * 32;
    float wd = __expf(clast - cum_s[q]) * dt_s[q];
    const unsigned short* gp = bcc + (rowb + q) * 256 + n0;
#pragma unroll
    for (int c4 = 0; c4 < 4; c4++){
      short8 v = *(const short8*)(gp + c4*8);
#pragma unroll
      for (int jj = 0; jj < 8; jj++)
        wBT[(n0 + c4*8 + jj)*CST + q] = f2h(h2f((unsigned short)v[jj]) * wd);
    }
  }
  __syncthreads();
  floatx4 acc[8] = {};
#pragma unroll
  for (int ks = 0; ks < 4; ks++){
    half8 af = *(const half8*)&xsT[(w*16 + l16)*CST + ks*32 + quad*8];
#pragma unroll
    for (int j = 0; j < 8; j++){
      half8 bfr = *(const half8*)&wBT[(j*16 + l16)*CST + ks*32 + quad*8];
      acc[j] = __builtin_amdgcn_mfma_f32_16x16x32_f16(af, bfr, acc[j], 0, 0, 0);
    }
  }
  size_t base = ((size_t)bc * 64 + h) * 8192;
#pragma unroll
  for (int j = 0; j < 8; j++){
    int n = j*16 + l16;
#pragma unroll
    for (int r = 0; r < 4; r++){
      int p = w*16 + quad*4 + r;
      st[base + p*128 + n] = f2h(acc[j][r]);
    }
  }
}

// ---------------- sequential inter-chunk scan (fp16 states -> Sprev, in place) ----------------
__global__ void k_scan(unsigned short* __restrict__ st, const float* __restrict__ cumb){
  int id = blockIdx.x * 256 + threadIdx.x;  // [0, 2*64*64*64)
  int n2 = id & 63, p = (id >> 6) & 63, h = (id >> 12) & 63, b = id >> 18;
  float S0 = 0.f, S1 = 0.f;
  for (int c = 0; c < NCHUNK; c++){
    int bc = b * NCHUNK + c;
    size_t idx = ((size_t)bc * 64 + h) * 8192 + (size_t)p * 128 + n2 * 2;
    float dec = __expf(cumb[((size_t)bc * QCH + 127) * 64 + h]);
    unsigned v = *(const unsigned*)&st[idx];
    float v0 = h2f((unsigned short)(v & 0xffff));
    float v1 = h2f((unsigned short)(v >> 16));
    unsigned o = (unsigned)f2h(S0) | ((unsigned)f2h(S1) << 16);
    *(unsigned*)&st[idx] = o;
    S0 = S0 * dec + v0;
    S1 = S1 * dec + v1;
  }
}

// ---------------- gate y*silu(z) + RMSNorm, in-place fp16 (vectorized) ----------
__global__ __launch_bounds__(256)
void k_gate(unsigned short* __restrict__ yb, const unsigned short* __restrict__ zb,
            const float* __restrict__ nw){
  __shared__ float red[4];
  int row = blockIdx.x, t = threadIdx.x;
  size_t base = (size_t)row * HIDN + t * 16;
  short8 y0 = *(const short8*)&yb[base], y1 = *(const short8*)&yb[base + 8];
  short8 z0 = *(const short8*)&zb[base], z1 = *(const short8*)&zb[base + 8];
  float vals[16], ss = 0.f;
#pragma unroll
  for (int j = 0; j < 8; j++){
    float y = h2f((unsigned short)y0[j]);
    float z = h2f((unsigned short)z0[j]);
    float v = y * (z / (1.f + __expf(-z)));
    vals[j] = v; ss += v * v;
  }
#pragma unroll
  for (int j = 0; j < 8; j++){
    float y = h2f((unsigned short)y1[j]);
    float z = h2f((unsigned short)z1[j]);
    float v = y * (z / (1.f + __expf(-z)));
    vals[8 + j] = v; ss += v * v;
  }
  for (int o = 32; o > 0; o >>= 1) ss += __shfl_down(ss, o, 64);
  int w = t >> 6, lane = t & 63;
  if (lane == 0) red[w] = ss;
  __syncthreads();
  float scale = rsqrtf((red[0] + red[1] + red[2] + red[3]) / (float)HIDN + 1e-5f);
  const float4 nw0 = *(const float4*)&nw[t*16];
  const float4 nw1 = *(const float4*)&nw[t*16 + 4];
  const float4 nw2 = *(const float4*)&nw[t*16 + 8];
  const float4 nw3 = *(const float4*)&nw[t*16 + 12];
  float nwv[16] = { nw0.x, nw0.y, nw0.z, nw0.w, nw1.x, nw1.y, nw1.z, nw1.w,
                    nw2.x, nw2.y, nw2.z, nw2.w, nw3.x, nw3.y, nw3.z, nw3.w };
  short8 o0, o1;
#pragma unroll
  for (int j = 0; j < 8; j++){
    o0[j] = (short)f2h(vals[j] * scale * nwv[j]);
    o1[j] = (short)f2h(vals[8 + j] * scale * nwv[8 + j]);
  }
  *(short8*)&yb[base]     = o0;
  *(short8*)&yb[base + 8] = o1;
}

extern "C" void kernel_launch(void* const* d_in, const int* in_sizes, int n_in,
                              void* d_out, int out_size, void* d_ws, size_t ws_size,
                              hipStream_t stream){
  const float* x      = (const float*)d_in[0];
  const float* Win    = (const float*)d_in[1];
  const float* convw  = (const float*)d_in[2];
  const float* dtbias = (const float*)d_in[3];
  const float* Alog   = (const float*)d_in[4];
  const float* Dp     = (const float*)d_in[5];
  const float* nw     = (const float*)d_in[6];
  const float* Wout   = (const float*)d_in[7];
  float* out = (float*)d_out;

  char* ws = (char*)d_ws;
  size_t off = 0;
  auto alloc = [&](size_t bytes)->void*{ void* p = ws + off; off += (bytes + 255) & ~(size_t)255; return p; };
  unsigned short* xw    = (unsigned short*)alloc((size_t)ROWS * DIMK * 2);   // 33.5 MB (dead after gemm1)
  unsigned short* winb  = (unsigned short*)alloc((size_t)8448 * DIMK * 2);   // 34.6 MB (dead after gemm1)
  float*          dtraw = (float*)alloc((size_t)ROWS * 64 * 4);              // 2.1 MB
  unsigned short* woutb = (unsigned short*)alloc((size_t)DIMK * HIDN * 2);   // 16.8 MB
  unsigned short* zbuf  = (unsigned short*)alloc((size_t)ROWS * HIDN * 2);   // 67.1 MB
  unsigned short* xsraw = (unsigned short*)alloc((size_t)ROWS * HIDN * 2);   // 67.1 MB (pre-conv xs -> post-conv xs -> y)
  unsigned short* bcraw = (unsigned short*)alloc((size_t)ROWS * 256 * 2);    // 4.2 MB
  unsigned short* bcc   = (unsigned short*)alloc((size_t)ROWS * 256 * 2);    // 4.2 MB
  unsigned short* halo  = (unsigned short*)alloc((size_t)64 * 3 * 4096 * 2); // 1.5 MB
  float*          dtb   = (float*)alloc((size_t)ROWS * 64 * 4);              // 2.1 MB
  float*          cumb  = (float*)alloc((size_t)ROWS * 64 * 4);              // 2.1 MB
  // total ~224.5 MiB; states (fp16, 67.1 MB) overlays dead xw+winb region
  unsigned short* st    = xw;
  unsigned short* ybuf  = xsraw;   // chunk1 writes y in-place over post-conv xs

  k_prep<<<41472, 256, 0, stream>>>(x, Win, Wout, xw, winb, woutb);
  k_dtraw<<<ROWS/16, 256, 0, stream>>>(x, Win, dtraw);
  k_gemm1<<<dim3(33*32), 512, 0, stream>>>(xw, winb, zbuf, xsraw, bcraw);
  k_mid<<<11280, 256, 0, stream>>>(bcraw, convw, bcc, xsraw, halo,
                                   dtraw, dtbias, Alog, dtb, cumb);
  k_chunk2<<<4096, 256, 0, stream>>>(xsraw, bcc, halo, convw, dtb, cumb, st);
  k_scan<<<2048, 256, 0, stream>>>(st, cumb);
  k_chunk1<<<4096, 256, 0, stream>>>(xsraw, bcc, dtb, cumb, Dp, st, ybuf);
  k_gate<<<ROWS, 256, 0, stream>>>(ybuf, zbuf, nw);
  k_gemm2<<<dim3(8*32), 512, 0, stream>>>(ybuf, woutb, out);
}

// Round 12
// 1043.607 us; speedup vs baseline: 1.1862x; 1.0051x over previous
//
#include <hip/hip_runtime.h>
#include <hip/hip_fp16.h>
#include <math.h>

// Problem constants
#define ROWS   8192        // B*L = 2*4096
#define DIMK   2048
#define HIDN   4096
#define QCH    128
#define NCHUNK 32          // L/Q per batch
#define CST    136         // chunk-kernel LDS row stride (shorts): 272B = 68 dwords,
                           // 68r mod 32 = 4r -> 16-row MFMA reads are 2-way (free)
#define RST    68          // raw-tile LDS row stride (shorts)

typedef __attribute__((ext_vector_type(8))) short short8;
typedef __attribute__((ext_vector_type(8))) _Float16 half8;
typedef __attribute__((ext_vector_type(4))) float floatx4;

static __device__ inline unsigned short f2h(float f){
  union { _Float16 h; unsigned short u; } v; v.h = (_Float16)f; return v.u;
}
static __device__ inline float h2f(unsigned short u){
  union { unsigned short u; _Float16 h; } v; v.u = u; return (float)v.h;
}
static __device__ inline void async_cp16(const void* g, void* l){
  __builtin_amdgcn_global_load_lds((const __attribute__((address_space(1))) void*)g,
                                   (__attribute__((address_space(3))) void*)l, 16, 0, 0);
}

// ---------------- merged fp32 -> fp16 cast for x, W_in[0:8448], W_out ----------
__global__ void k_prep(const float* __restrict__ x, const float* __restrict__ Win,
                       const float* __restrict__ Wout, unsigned short* __restrict__ xw,
                       unsigned short* __restrict__ winb, unsigned short* __restrict__ woutb){
  int blk = blockIdx.x, t = threadIdx.x;
  const float* src; unsigned short* dst; int i;
  if (blk < 16384){ src = x;    dst = xw;    i = blk * 256 + t; }
  else if (blk < 33280){ src = Win;  dst = winb;  i = (blk - 16384) * 256 + t; }
  else { src = Wout; dst = woutb; i = (blk - 33280) * 256 + t; }
  float4 v = ((const float4*)src)[i];
  unsigned long long p = (unsigned long long)f2h(v.x)
                       | ((unsigned long long)f2h(v.y) << 16)
                       | ((unsigned long long)f2h(v.z) << 32)
                       | ((unsigned long long)f2h(v.w) << 48);
  ((unsigned long long*)dst)[i] = p;
}

// ---------------- exact fp32 dt_raw = x @ W_in[8448:8512].T ----------------
// R2-measured config (87 us): 1024 blocks x 8 rows, wave w owns 2 rows,
// 4 blocks/CU (33.8KB LDS) = 4 waves/SIMD latency hiding. The R6 512-block
// variant halved occupancy and cost ~+45 us (inferred from R5->R6 delta).
#define DT_KT 128
__global__ __launch_bounds__(256)
void k_dtraw(const float* __restrict__ x, const float* __restrict__ Win,
             float* __restrict__ dtraw){
  __shared__ float ws[64 * (DT_KT + 4)];          // stride 132 floats
  const int t = threadIdx.x;
  const int lane = t & 63, w = t >> 6;
  const int r0 = blockIdx.x * 8;
  const int rw = __builtin_amdgcn_readfirstlane(r0 + w * 2);
  float acc0 = 0.f, acc1 = 0.f;
  for (int k0 = 0; k0 < DIMK; k0 += DT_KT){
    __syncthreads();                              // previous tile's reads done
#pragma unroll
    for (int l = 0; l < 8; l++){
      int fidx = (l * 256 + t) * 4;               // 0..8191 floats
      int row = fidx >> 7, col = fidx & 127;
      *(float4*)&ws[row * 132 + col] =
          *(const float4*)&Win[(size_t)(8448 + row) * DIMK + k0 + col];
    }
    __syncthreads();
    const float* xa = x + (size_t)rw * DIMK + k0;
    const float* xb = xa + DIMK;
#pragma unroll 8
    for (int kk = 0; kk < DT_KT; kk += 4){
      float4 wv = *(const float4*)&ws[lane * 132 + kk];
      float4 va = *(const float4*)&xa[kk];
      float4 vb = *(const float4*)&xb[kk];
      acc0 += wv.x*va.x + wv.y*va.y + wv.z*va.z + wv.w*va.w;
      acc1 += wv.x*vb.x + wv.y*vb.y + wv.z*vb.z + wv.w*vb.w;
    }
  }
  dtraw[(size_t)rw * 64 + lane]       = acc0;
  dtraw[(size_t)(rw + 1) * 64 + lane] = acc1;
}

// ---------------- asm LDS read helpers (opaque to alias analysis) ----------------
static __device__ inline unsigned ldsaddr(const void* p){
  return (unsigned)(size_t)(const __attribute__((address_space(3))) void*)p;
}
static __device__ inline floatx4 dsr128(unsigned a){
  floatx4 d;
  asm volatile("ds_read_b128 %0, %1" : "=v"(d) : "v"(a));
  return d;
}
static __device__ inline half8 as_h8(floatx4 f){
  union { floatx4 f; half8 h; } u; u.f = f; return u.h;
}

// ---------------- 256x256 MFMA GEMM core, 4-phase/K-tile (R7 local optimum) ----
template<int KD>
__device__ inline void gemm256_core(const unsigned short* __restrict__ A,
                                    const unsigned short* __restrict__ B,
                                    int row0, int col0,
                                    unsigned short* sA, unsigned short* sB,
                                    floatx4 (&acc)[8][4], int t){
  const int lane = t & 63, wid = t >> 6;
  const int wm = wid >> 2, wn = wid & 3;
  const int quad = lane >> 4, l16 = lane & 15;
  const int srow  = t >> 3;                    // 0..63: row within 64-row stage block
  const int sslot = (t & 7) ^ (srow & 7);      // pre-swizzled global 16B slot
  constexpr int NT = KD / 64;

  auto stageA = [&](int d, int half, int kt){
    unsigned short* dst = sA + d*256*64 + half*128*64;
    const unsigned short* src = A + (size_t)(row0 + half*128) * KD + kt*64;
#pragma unroll
    for (int i = 0; i < 2; i++)
      async_cp16(src + (size_t)(i*64 + srow) * KD + sslot*8,
                 dst + ((size_t)i*512 + t)*8);
  };
  auto stageB = [&](int d, int half, int kt){
    unsigned short* dst = sB + d*256*64 + half*128*64;
    const unsigned short* src = B + (size_t)(col0 + half*128) * KD + kt*64;
#pragma unroll
    for (int i = 0; i < 2; i++)
      async_cp16(src + (size_t)(i*64 + srow) * KD + sslot*8,
                 dst + ((size_t)i*512 + t)*8);
  };

  const unsigned sAbase = ldsaddr(sA), sBbase = ldsaddr(sB);
  floatx4 af[8][2], bf[4][2];
  auto rdA = [&](unsigned base, int fr, int ks) -> floatx4 {
    return dsr128(base + 2u*(unsigned)((fr*16 + l16)*64 + (((ks*4+quad)^(l16&7))*8)));
  };
  auto rdB = [&](unsigned base, int fc, int ks) -> floatx4 {
    return dsr128(base + 2u*(unsigned)((fc*16 + l16)*64 + (((ks*4+quad)^(l16&7))*8)));
  };
  auto mmac = [&](int mh, int nh){
    __builtin_amdgcn_s_setprio(1);
#pragma unroll
    for (int mm = 0; mm < 4; mm++)
#pragma unroll
      for (int nn = 0; nn < 2; nn++)
#pragma unroll
        for (int ks = 0; ks < 2; ks++)
          acc[mh*4+mm][nh*2+nn] = __builtin_amdgcn_mfma_f32_16x16x32_f16(
              as_h8(af[mh*4+mm][ks]), as_h8(bf[nh*2+nn][ks]), acc[mh*4+mm][nh*2+nn], 0, 0, 0);
    __builtin_amdgcn_s_setprio(0);
  };

  // prologue: tile0 full -> buf0 (8 loads), tile1 A -> buf1 (4 loads)
  stageA(0,0,0); stageA(0,1,0); stageB(0,0,0); stageB(0,1,0);
  stageA(1,0,1); stageA(1,1,1);
  asm volatile("s_waitcnt vmcnt(4)" ::: "memory");   // tile0's 8 loads landed
  __builtin_amdgcn_s_barrier();

  for (int T = 0; T < NT; T++){
    const int cur = T & 1;
    const unsigned aAd = sAbase + 2u*(unsigned)(cur*256*64 + wm*128*64);
    const unsigned bAd = sBbase + 2u*(unsigned)(cur*256*64 + wn*64*64);
    // ---------------- phase 0: read A0-3,B0-1 | stage B-top(T+1) ----------------
#pragma unroll
    for (int fr = 0; fr < 4; fr++)
#pragma unroll
      for (int ks = 0; ks < 2; ks++)
        af[fr][ks] = rdA(aAd, fr, ks);
#pragma unroll
    for (int fc = 0; fc < 2; fc++)
#pragma unroll
      for (int ks = 0; ks < 2; ks++)
        bf[fc][ks] = rdB(bAd, fc, ks);
    if (T + 1 < NT) stageB(cur^1, 0, T+1);
    __builtin_amdgcn_s_barrier();
    asm volatile("s_waitcnt lgkmcnt(0)" ::: "memory");
    __builtin_amdgcn_sched_barrier(0);
    mmac(0, 0);
    __builtin_amdgcn_s_barrier();
    // ---------------- phase 1: read A4-7 | stage B-bot(T+1) ----------------
#pragma unroll
    for (int fr = 4; fr < 8; fr++)
#pragma unroll
      for (int ks = 0; ks < 2; ks++)
        af[fr][ks] = rdA(aAd, fr, ks);
    if (T + 1 < NT) stageB(cur^1, 1, T+1);
    __builtin_amdgcn_s_barrier();
    asm volatile("s_waitcnt lgkmcnt(0)" ::: "memory");
    __builtin_amdgcn_sched_barrier(0);
    mmac(1, 0);
    __builtin_amdgcn_s_barrier();
    // ---------------- phase 2: read B2-3 ----------------
#pragma unroll
    for (int fc = 2; fc < 4; fc++)
#pragma unroll
      for (int ks = 0; ks < 2; ks++)
        bf[fc][ks] = rdB(bAd, fc, ks);
    __builtin_amdgcn_s_barrier();
    asm volatile("s_waitcnt lgkmcnt(0)" ::: "memory");
    __builtin_amdgcn_sched_barrier(0);
    mmac(0, 1);
    __builtin_amdgcn_s_barrier();
    // ---------------- phase 3: stage A(T+2), counted vmcnt ----------------
    if (T + 2 < NT){
      stageA(cur, 0, T+2); stageA(cur, 1, T+2);
      asm volatile("s_waitcnt vmcnt(4)" ::: "memory");
    } else if (T + 1 < NT){
      asm volatile("s_waitcnt vmcnt(0)" ::: "memory");
    }
    __builtin_amdgcn_s_barrier();
    mmac(1, 1);
    __builtin_amdgcn_s_barrier();
  }
}

// ---------------- GEMM1: routed fp16 epilogue (z | xs | bc) ----------------
__global__ __launch_bounds__(512, 2)
void k_gemm1(const unsigned short* __restrict__ A, const unsigned short* __restrict__ B,
             unsigned short* __restrict__ zbuf, unsigned short* __restrict__ xsraw,
             unsigned short* __restrict__ bcraw){
  __shared__ __align__(16) unsigned short sA[2*256*64];
  __shared__ __align__(16) unsigned short sB[2*256*64];
  const int t = threadIdx.x;
  // bijective XCD swizzle: 1056 = 8 * 132
  int swz = (blockIdx.x % 8) * 132 + blockIdx.x / 8;
  const int row0 = (swz & 31) * 256, col0 = (swz >> 5) * 256;
  floatx4 acc[8][4] = {};
  gemm256_core<DIMK>(A, B, row0, col0, sA, sB, acc, t);
  const int lane = t & 63, wid = t >> 6;
  const int wm = wid >> 2, wn = wid & 3;
  const int quad = lane >> 4, l16 = lane & 15;
  unsigned short* dst; int cbase, ldd;
  if (col0 < 4096){ dst = zbuf; cbase = 0; ldd = 4096; }
  else if (col0 < 8192){ dst = xsraw; cbase = 4096; ldd = 4096; }
  else { dst = bcraw; cbase = 8192; ldd = 256; }
#pragma unroll
  for (int m = 0; m < 8; m++)
#pragma unroll
    for (int n = 0; n < 4; n++){
      int rb = row0 + wm*128 + m*16 + quad*4;
      int cc = col0 + wn*64 + n*16 + l16 - cbase;
#pragma unroll
      for (int r = 0; r < 4; r++)
        dst[(size_t)(rb + r) * ldd + cc] = f2h(acc[m][n][r]);
    }
}

// ---------------- GEMM2: fp32 epilogue to d_out ----------------
__global__ __launch_bounds__(512, 2)
void k_gemm2(const unsigned short* __restrict__ A, const unsigned short* __restrict__ B,
             float* __restrict__ C){
  __shared__ __align__(16) unsigned short sA[2*256*64];
  __shared__ __align__(16) unsigned short sB[2*256*64];
  const int t = threadIdx.x;
  // bijective XCD swizzle: 256 = 8 * 32
  int swz = (blockIdx.x % 8) * 32 + blockIdx.x / 8;
  const int row0 = (swz & 31) * 256, col0 = (swz >> 5) * 256;
  floatx4 acc[8][4] = {};
  gemm256_core<HIDN>(A, B, row0, col0, sA, sB, acc, t);
  const int lane = t & 63, wid = t >> 6;
  const int wm = wid >> 2, wn = wid & 3;
  const int quad = lane >> 4, l16 = lane & 15;
#pragma unroll
  for (int m = 0; m < 8; m++)
#pragma unroll
    for (int n = 0; n < 4; n++){
      int rb = row0 + wm*128 + m*16 + quad*4;
      int cc = col0 + wn*64 + n*16 + l16;
#pragma unroll
      for (int r = 0; r < 4; r++)
        C[(size_t)(rb + r) * DIMK + cc] = acc[m][n][r];
    }
}

// ---------------- merged post-gemm1 small kernels ----------------
__global__ void k_mid(const unsigned short* __restrict__ bcraw, const float* __restrict__ cw,
                      unsigned short* __restrict__ bcc,
                      const unsigned short* __restrict__ xsraw, unsigned short* __restrict__ halo,
                      const float* __restrict__ dtraw, const float* __restrict__ dtbias,
                      const float* __restrict__ Alog, float* __restrict__ dtb,
                      float* __restrict__ cumb){
  int blk = blockIdx.x, t = threadIdx.x;
  if (blk < 8192){
    int row = blk, c = t;
    int tl = row & 4095;
    const float4 wv = *(const float4*)&cw[(size_t)(4096 + c) * 4];
    const unsigned short* col = bcraw + c;
    size_t rb = (size_t)row * 256;
    float a = h2f(col[rb]) * wv.w;
    if (tl >= 1) a += h2f(col[rb - 256]) * wv.z;
    if (tl >= 2) a += h2f(col[rb - 512]) * wv.y;
    if (tl >= 3) a += h2f(col[rb - 768]) * wv.x;
    bcc[rb + c] = f2h(a / (1.f + __expf(-a)));
  } else if (blk < 11264){
    int idx = blk - 8192;                       // [0,3072) = 16 x 3 x 64
    int col = (idx & 15) * 256 + t;
    int slot = (idx >> 4) % 3;
    int bc = idx / 48;
    long r = (long)bc * QCH - 3 + slot;
    if (r >= 0)
      halo[((size_t)bc * 3 + slot) * 4096 + col] = xsraw[(size_t)r * 4096 + col];
  } else {
    int lb = blk - 11264;                       // [0,16): 4 chunks x 64 heads per block
    int bc = lb * 4 + (t >> 6);
    int h = t & 63;
    float bias = dtbias[h];
    float A = -__expf(Alog[h]);
    float run = 0.f;
    size_t rowb = (size_t)bc * QCH;
    for (int q = 0; q < QCH; q++){
      float dr = dtraw[(rowb + q) * 64 + h] + bias;
      float dt = dr > 20.f ? dr : log1pf(__expf(dr));
      dtb[(rowb + q) * 64 + h] = dt;
      run += dt * A;
      cumb[(rowb + q) * 64 + h] = run;
    }
  }
}

// ---------------- per-(chunk,head): CB -> M -> Yd; + Yoff from Sprev; y = Yd+Yoff+D*xs ----------------
// xsc = POST-conv xs (chunk2 wrote it back in place over xsraw) in [row][col] layout.
__global__ __launch_bounds__(256, 2)
void k_chunk1(const unsigned short* __restrict__ xsc, const unsigned short* __restrict__ bcc,
              const float* __restrict__ dtb, const float* __restrict__ cumb,
              const float* __restrict__ Dp, const unsigned short* __restrict__ st,
              unsigned short* __restrict__ ybuf){
  __shared__ __align__(16) unsigned short Ml[128*CST];
  __shared__ __align__(16) unsigned short xsT[64*CST];
  __shared__ float cum_s[128], dt_s[128];
  const int blk = blockIdx.x, h = blk & 63, bc = blk >> 6;
  const size_t rowb = (size_t)bc * QCH;
  const int t = threadIdx.x, w = t >> 6, lane = t & 63, quad = lane >> 4, l16 = lane & 15;
  const int wrow = w * 32;
  if (t < 128){ cum_s[t] = cumb[(rowb + t)*64 + h]; dt_s[t] = dtb[(rowb + t)*64 + h]; }
  __syncthreads();
  // copy-transpose post-conv xs tile into xsT (no conv recompute)
#pragma unroll
  for (int it = 0; it < 2; it++){
    int idx = it * 256 + t;
    int q = idx & 127, p0 = (idx >> 7) * 16;
    const unsigned short* cur = xsc + (rowb + q) * 4096 + h * 64 + p0;
    short8 c0 = *(const short8*)cur, c1 = *(const short8*)(cur + 8);
#pragma unroll
    for (int j = 0; j < 16; j++)
      xsT[(p0 + j) * CST + q] = (unsigned short)(j < 8 ? c0[j] : c1[j-8]);
  }
  // CB = C @ B^T from post-conv bcc
  floatx4 acc[2][8] = {};
  const unsigned short* Cb = bcc + rowb * 256 + 128;
  const unsigned short* Bb = bcc + rowb * 256;
#pragma unroll
  for (int ks = 0; ks < 4; ks++){
    half8 af[2];
#pragma unroll
    for (int i = 0; i < 2; i++)
      af[i] = *(const half8*)(Cb + (size_t)(wrow + i*16 + l16) * 256 + ks*32 + quad*8);
#pragma unroll
    for (int j = 0; j < 8; j++){
      half8 bfr = *(const half8*)(Bb + (size_t)(j*16 + l16) * 256 + ks*32 + quad*8);
#pragma unroll
      for (int i = 0; i < 2; i++)
        acc[i][j] = __builtin_amdgcn_mfma_f32_16x16x32_f16(af[i], bfr, acc[i][j], 0, 0, 0);
    }
  }
  // M = CB * exp(cum_i - cum_j) * dt_j, causal, -> LDS fp16
#pragma unroll
  for (int i = 0; i < 2; i++)
#pragma unroll
    for (int j = 0; j < 8; j++){
      int jc = j*16 + l16;
      float dtj = dt_s[jc], cj = cum_s[jc];
#pragma unroll
      for (int r = 0; r < 4; r++){
        int ir = wrow + i*16 + quad*4 + r;
        float m = (ir >= jc) ? acc[i][j][r] * __expf(cum_s[ir] - cj) * dtj : 0.f;
        Ml[ir * CST + jc] = f2h(m);
      }
    }
  __syncthreads();
  // Yd = M @ xs
  floatx4 accY[2][4] = {};
#pragma unroll
  for (int ks = 0; ks < 4; ks++){
    half8 af[2], bfr[4];
#pragma unroll
    for (int i = 0; i < 2; i++)
      af[i] = *(const half8*)&Ml[(wrow + i*16 + l16)*CST + ks*32 + quad*8];
#pragma unroll
    for (int p = 0; p < 4; p++)
      bfr[p] = *(const half8*)&xsT[(p*16 + l16)*CST + ks*32 + quad*8];
#pragma unroll
    for (int i = 0; i < 2; i++)
#pragma unroll
      for (int p = 0; p < 4; p++)
        accY[i][p] = __builtin_amdgcn_mfma_f32_16x16x32_f16(af[i], bfr[p], accY[i][p], 0, 0, 0);
  }
  // ---- Yoff: stage Sprev (fp16) into Ml's LDS (stride CST), then C @ Sprev^T ----
  __syncthreads();                       // all Yd reads of Ml done
  unsigned short* Sp = Ml;               // reuse (64*CST <= 128*CST)
  {
    size_t base = ((size_t)bc * 64 + h) * 8192;
#pragma unroll
    for (int it = 0; it < 4; it++){
      int flat = it * 256 + t;           // [0,1024): 64 rows x 16 copies of 8
      int row = flat >> 4, col = (flat & 15) * 8;
      *(short8*)&Sp[row * CST + col] = *(const short8*)&st[base + (size_t)row * 128 + col];
    }
  }
  __syncthreads();
  floatx4 accO[2][4] = {};
#pragma unroll
  for (int ks = 0; ks < 4; ks++){
    half8 af[2], bfr[4];
#pragma unroll
    for (int i = 0; i < 2; i++)
      af[i] = *(const half8*)(Cb + (size_t)(wrow + i*16 + l16) * 256 + ks*32 + quad*8);
#pragma unroll
    for (int p = 0; p < 4; p++)
      bfr[p] = *(const half8*)&Sp[(p*16 + l16)*CST + ks*32 + quad*8];
#pragma unroll
    for (int i = 0; i < 2; i++)
#pragma unroll
      for (int p = 0; p < 4; p++)
        accO[i][p] = __builtin_amdgcn_mfma_f32_16x16x32_f16(af[i], bfr[p], accO[i][p], 0, 0, 0);
  }
  float Dh = Dp[h];
#pragma unroll
  for (int i = 0; i < 2; i++)
#pragma unroll
    for (int p = 0; p < 4; p++){
      int pc = p*16 + l16;
#pragma unroll
      for (int r = 0; r < 4; r++){
        int ir = wrow + i*16 + quad*4 + r;
        float y = accY[i][p][r] + __expf(cum_s[ir]) * accO[i][p][r] + Dh * h2f(xsT[pc*CST + ir]);
        ybuf[(rowb + ir) * (size_t)HIDN + h*64 + pc] = f2h(y);
      }
    }
}

// ---------------- per-(chunk,head): states[p][n] = sum_q xs[q][p]*wdec_q*B[q][n] ----------------
// Raw-tile staging: block's 131x64 pre-conv slice (rows rowb-3..rowb+127; lds
// row r <-> global row rowb+r-3; rows<3 from halo) read ONCE into LDS, conv
// computed from LDS (was 4 global tap reads/elem), post-conv written back to
// global directly from registers. Arithmetic expression-identical.
__global__ __launch_bounds__(256, 2)
void k_chunk2(unsigned short* __restrict__ xsraw, const unsigned short* __restrict__ bcc,
              const unsigned short* __restrict__ halo, const float* __restrict__ cw,
              const float* __restrict__ dtb, const float* __restrict__ cumb,
              unsigned short* __restrict__ st){
  __shared__ __align__(16) unsigned short wBT[128*CST];
  __shared__ __align__(16) unsigned short xsT[64*CST];
  __shared__ __align__(16) unsigned short xsRaw[131*RST];
  __shared__ float cum_s[128], dt_s[128];
  __shared__ float cws[64*4];
  const int blk = blockIdx.x, h = blk & 63, bc = blk >> 6;
  const size_t rowb = (size_t)bc * QCH;
  const int t = threadIdx.x, w = t >> 6, lane = t & 63, quad = lane >> 4, l16 = lane & 15;
  if (t < 128){ cum_s[t] = cumb[(rowb + t)*64 + h]; dt_s[t] = dtb[(rowb + t)*64 + h]; }
  if (t < 64) *(float4*)&cws[t*4] = *(const float4*)&cw[((size_t)h*64 + t)*4];
  // stage raw slice: 131 rows x 8 chunks of 16B = 1048 chunks
#pragma unroll
  for (int it = 0; it < 5; it++){
    int flat = it * 256 + t;
    if (flat < 1048){
      int row = flat >> 3, c8 = (flat & 7) * 8;
      const unsigned short* src = (row < 3)
        ? halo + ((size_t)bc * 3 + row) * 4096 + h * 64 + c8
        : xsraw + (rowb + row - 3) * 4096 + h * 64 + c8;
      *(short8*)&xsRaw[row * RST + c8] = *(const short8*)src;
    }
  }
  __syncthreads();
  // conv + SiLU from LDS; write xsT (transposed) + post-conv back to global
  const int tl0 = (bc & 31) * QCH;
#pragma unroll
  for (int it = 0; it < 2; it++){
    int idx = it * 256 + t;
    int q = idx & 127, p0 = (idx >> 7) * 16;
    int tl = tl0 + q;
    int lr = q + 3;
    float f1 = (tl >= 1) ? 1.f : 0.f;
    float f2 = (tl >= 2) ? 1.f : 0.f;
    float f3 = (tl >= 3) ? 1.f : 0.f;
    short8 c0 = *(const short8*)&xsRaw[lr*RST + p0],     c1 = *(const short8*)&xsRaw[lr*RST + p0 + 8];
    short8 a0 = *(const short8*)&xsRaw[(lr-1)*RST + p0], a1 = *(const short8*)&xsRaw[(lr-1)*RST + p0 + 8];
    short8 b0 = *(const short8*)&xsRaw[(lr-2)*RST + p0], b1 = *(const short8*)&xsRaw[(lr-2)*RST + p0 + 8];
    short8 d0 = *(const short8*)&xsRaw[(lr-3)*RST + p0], d1 = *(const short8*)&xsRaw[(lr-3)*RST + p0 + 8];
    short8 w0, w1;
#pragma unroll
    for (int j = 0; j < 16; j++){
      int col = p0 + j;
      const float* wp = cws + col * 4;
      float vc = h2f((unsigned short)(j < 8 ? c0[j] : c1[j-8]));
      float v1 = h2f((unsigned short)(j < 8 ? a0[j] : a1[j-8]));
      float v2 = h2f((unsigned short)(j < 8 ? b0[j] : b1[j-8]));
      float v3 = h2f((unsigned short)(j < 8 ? d0[j] : d1[j-8]));
      float a = vc * wp[3] + f1 * v1 * wp[2] + f2 * v2 * wp[1] + f3 * v3 * wp[0];
      float s = a / (1.f + __expf(-a));
      unsigned short hv = f2h(s);
      xsT[col * CST + q] = hv;
      if (j < 8) w0[j] = (short)hv; else w1[j-8] = (short)hv;
    }
    unsigned short* g = xsraw + (rowb + q) * 4096 + h * 64 + p0;
    *(short8*)g = w0;
    *(short8*)(g + 8) = w1;
  }
  float clast = cum_s[127];
#pragma unroll
  for (int it = 0; it < 2; it++){                 // wBT[n][q] = B[q][n]*wdec_q
    int idx = it * 256 + t;
    int q = idx & 127, n0 = (idx >> 7) * 32;
    float wd = __expf(clast - cum_s[q]) * dt_s[q];
    const unsigned short* gp = bcc + (rowb + q) * 256 + n0;
#pragma unroll
    for (int c4 = 0; c4 < 4; c4++){
      short8 v = *(const short8*)(gp + c4*8);
#pragma unroll
      for (int jj = 0; jj < 8; jj++)
        wBT[(n0 + c4*8 + jj)*CST + q] = f2h(h2f((unsigned short)v[jj]) * wd);
    }
  }
  __syncthreads();
  floatx4 acc[8] = {};
#pragma unroll
  for (int ks = 0; ks < 4; ks++){
    half8 af = *(const half8*)&xsT[(w*16 + l16)*CST + ks*32 + quad*8];
#pragma unroll
    for (int j = 0; j < 8; j++){
      half8 bfr = *(const half8*)&wBT[(j*16 + l16)*CST + ks*32 + quad*8];
      acc[j] = __builtin_amdgcn_mfma_f32_16x16x32_f16(af, bfr, acc[j], 0, 0, 0);
    }
  }
  size_t base = ((size_t)bc * 64 + h) * 8192;
#pragma unroll
  for (int j = 0; j < 8; j++){
    int n = j*16 + l16;
#pragma unroll
    for (int r = 0; r < 4; r++){
      int p = w*16 + quad*4 + r;
      st[base + p*128 + n] = f2h(acc[j][r]);
    }
  }
}

// ---------------- sequential inter-chunk scan (fp16 states -> Sprev, in place) ----------------
__global__ void k_scan(unsigned short* __restrict__ st, const float* __restrict__ cumb){
  int id = blockIdx.x * 256 + threadIdx.x;  // [0, 2*64*64*64)
  int n2 = id & 63, p = (id >> 6) & 63, h = (id >> 12) & 63, b = id >> 18;
  float S0 = 0.f, S1 = 0.f;
  for (int c = 0; c < NCHUNK; c++){
    int bc = b * NCHUNK + c;
    size_t idx = ((size_t)bc * 64 + h) * 8192 + (size_t)p * 128 + n2 * 2;
    float dec = __expf(cumb[((size_t)bc * QCH + 127) * 64 + h]);
    unsigned v = *(const unsigned*)&st[idx];
    float v0 = h2f((unsigned short)(v & 0xffff));
    float v1 = h2f((unsigned short)(v >> 16));
    unsigned o = (unsigned)f2h(S0) | ((unsigned)f2h(S1) << 16);
    *(unsigned*)&st[idx] = o;
    S0 = S0 * dec + v0;
    S1 = S1 * dec + v1;
  }
}

// ---------------- gate y*silu(z) + RMSNorm, in-place fp16 (vectorized) ----------
__global__ __launch_bounds__(256)
void k_gate(unsigned short* __restrict__ yb, const unsigned short* __restrict__ zb,
            const float* __restrict__ nw){
  __shared__ float red[4];
  int row = blockIdx.x, t = threadIdx.x;
  size_t base = (size_t)row * HIDN + t * 16;
  short8 y0 = *(const short8*)&yb[base], y1 = *(const short8*)&yb[base + 8];
  short8 z0 = *(const short8*)&zb[base], z1 = *(const short8*)&zb[base + 8];
  float vals[16], ss = 0.f;
#pragma unroll
  for (int j = 0; j < 8; j++){
    float y = h2f((unsigned short)y0[j]);
    float z = h2f((unsigned short)z0[j]);
    float v = y * (z / (1.f + __expf(-z)));
    vals[j] = v; ss += v * v;
  }
#pragma unroll
  for (int j = 0; j < 8; j++){
    float y = h2f((unsigned short)y1[j]);
    float z = h2f((unsigned short)z1[j]);
    float v = y * (z / (1.f + __expf(-z)));
    vals[8 + j] = v; ss += v * v;
  }
  for (int o = 32; o > 0; o >>= 1) ss += __shfl_down(ss, o, 64);
  int w = t >> 6, lane = t & 63;
  if (lane == 0) red[w] = ss;
  __syncthreads();
  float scale = rsqrtf((red[0] + red[1] + red[2] + red[3]) / (float)HIDN + 1e-5f);
  const float4 nw0 = *(const float4*)&nw[t*16];
  const float4 nw1 = *(const float4*)&nw[t*16 + 4];
  const float4 nw2 = *(const float4*)&nw[t*16 + 8];
  const float4 nw3 = *(const float4*)&nw[t*16 + 12];
  float nwv[16] = { nw0.x, nw0.y, nw0.z, nw0.w, nw1.x, nw1.y, nw1.z, nw1.w,
                    nw2.x, nw2.y, nw2.z, nw2.w, nw3.x, nw3.y, nw3.z, nw3.w };
  short8 o0, o1;
#pragma unroll
  for (int j = 0; j < 8; j++){
    o0[j] = (short)f2h(vals[j] * scale * nwv[j]);
    o1[j] = (short)f2h(vals[8 + j] * scale * nwv[8 + j]);
  }
  *(short8*)&yb[base]     = o0;
  *(short8*)&yb[base + 8] = o1;
}

extern "C" void kernel_launch(void* const* d_in, const int* in_sizes, int n_in,
                              void* d_out, int out_size, void* d_ws, size_t ws_size,
                              hipStream_t stream){
  const float* x      = (const float*)d_in[0];
  const float* Win    = (const float*)d_in[1];
  const float* convw  = (const float*)d_in[2];
  const float* dtbias = (const float*)d_in[3];
  const float* Alog   = (const float*)d_in[4];
  const float* Dp     = (const float*)d_in[5];
  const float* nw     = (const float*)d_in[6];
  const float* Wout   = (const float*)d_in[7];
  float* out = (float*)d_out;

  char* ws = (char*)d_ws;
  size_t off = 0;
  auto alloc = [&](size_t bytes)->void*{ void* p = ws + off; off += (bytes + 255) & ~(size_t)255; return p; };
  unsigned short* xw    = (unsigned short*)alloc((size_t)ROWS * DIMK * 2);   // 33.5 MB (dead after gemm1)
  unsigned short* winb  = (unsigned short*)alloc((size_t)8448 * DIMK * 2);   // 34.6 MB (dead after gemm1)
  float*          dtraw = (float*)alloc((size_t)ROWS * 64 * 4);              // 2.1 MB
  unsigned short* woutb = (unsigned short*)alloc((size_t)DIMK * HIDN * 2);   // 16.8 MB
  unsigned short* zbuf  = (unsigned short*)alloc((size_t)ROWS * HIDN * 2);   // 67.1 MB
  unsigned short* xsraw = (unsigned short*)alloc((size_t)ROWS * HIDN * 2);   // 67.1 MB (pre-conv xs -> post-conv xs -> y)
  unsigned short* bcraw = (unsigned short*)alloc((size_t)ROWS * 256 * 2);    // 4.2 MB
  unsigned short* bcc   = (unsigned short*)alloc((size_t)ROWS * 256 * 2);    // 4.2 MB
  unsigned short* halo  = (unsigned short*)alloc((size_t)64 * 3 * 4096 * 2); // 1.5 MB
  float*          dtb   = (float*)alloc((size_t)ROWS * 64 * 4);              // 2.1 MB
  float*          cumb  = (float*)alloc((size_t)ROWS * 64 * 4);              // 2.1 MB
  // total ~224.5 MiB; states (fp16, 67.1 MB) overlays dead xw+winb region
  unsigned short* st    = xw;
  unsigned short* ybuf  = xsraw;   // chunk1 writes y in-place over post-conv xs

  k_prep<<<41472, 256, 0, stream>>>(x, Win, Wout, xw, winb, woutb);
  k_dtraw<<<ROWS/8, 256, 0, stream>>>(x, Win, dtraw);
  k_gemm1<<<dim3(33*32), 512, 0, stream>>>(xw, winb, zbuf, xsraw, bcraw);
  k_mid<<<11280, 256, 0, stream>>>(bcraw, convw, bcc, xsraw, halo,
                                   dtraw, dtbias, Alog, dtb, cumb);
  k_chunk2<<<4096, 256, 0, stream>>>(xsraw, bcc, halo, convw, dtb, cumb, st);
  k_scan<<<2048, 256, 0, stream>>>(st, cumb);
  k_chunk1<<<4096, 256, 0, stream>>>(xsraw, bcc, dtb, cumb, Dp, st, ybuf);
  k_gate<<<ROWS, 256, 0, stream>>>(ybuf, zbuf, nw);
  k_gemm2<<<dim3(8*32), 512, 0, stream>>>(ybuf, woutb, out);
}